// Round 16
// baseline (193.279 us; speedup 1.0000x reference)
//
#include <hip/hip_runtime.h>
#include <hip/hip_bf16.h>

typedef _Float16 f16;
typedef _Float16 f16x2 __attribute__((ext_vector_type(2)));
typedef _Float16 f16x4 __attribute__((ext_vector_type(4)));
typedef _Float16 f16x8 __attribute__((ext_vector_type(8)));
typedef float f32x4 __attribute__((ext_vector_type(4)));

// cvt_pkrtz returns __fp16 ext_vector(2); re-cast to our f16x2 (same bits).
__device__ __forceinline__ f16x2 pkrtz(float a, float b) {
    auto r = __builtin_amdgcn_cvt_pkrtz(a, b);
    f16x2 o; o[0] = (f16)r[0]; o[1] = (f16)r[1];
    return o;
}

#define XT_ROWS 1027
#define XT_BSTRIDE (XT_ROWS * 1024)   // elems per batch

// ---------------------------------------------------------------------------
// global -> LDS direct (16B per lane, wave-uniform LDS base + lane*16)
// ---------------------------------------------------------------------------
__device__ __forceinline__ void gload16(const f16* g, f16* l) {
    __builtin_amdgcn_global_load_lds(
        (const __attribute__((address_space(1))) void*)g,
        (__attribute__((address_space(3))) void*)l, 16, 0, 0);
}

// ---------------------------------------------------------------------------
// Stage a 128x64 f16 tile from row-major src (ld elems) into 16KB LDS.
// XOR-swizzle on the SOURCE col, same XOR on the read side (involution).
// Slot s (0..1023) -> LDS elems [8s,8s+8) ; source (row=s>>3, col=((s&7)^
// (row&7))*8).
// ---------------------------------------------------------------------------
__device__ __forceinline__ void stage_tile(const f16* src, int ld, f16* lds)
{
    const int tid = threadIdx.x;
    const int w512 = (tid >> 6) << 9;          // wave base (f16 elems)
    #pragma unroll
    for (int q = 0; q < 4; ++q) {
        const int s = q * 256 + tid;           // 16B slot id, 0..1023
        const int row = s >> 3;
        const int col = ((s & 7) ^ (row & 7)) << 3;
        gload16(src + row * ld + col, lds + (q << 11) + w512);
    }
}

// ---------------------------------------------------------------------------
// Stage a 64x64 f16 tile (8KB) the same way (512 slots, 2 per thread).
// ---------------------------------------------------------------------------
__device__ __forceinline__ void stage64(const f16* src, int ld, f16* lds)
{
    const int tid = threadIdx.x;
    const int w512 = (tid >> 6) << 9;
    #pragma unroll
    for (int q = 0; q < 2; ++q) {
        const int s = q * 256 + tid;           // 16B slot id, 0..511
        const int row = s >> 3;
        const int col = ((s & 7) ^ (row & 7)) << 3;
        gload16(src + row * ld + col, lds + (q << 11) + w512);
    }
}

// ---------------------------------------------------------------------------
// f32 A-tile reg-staging (fused convert): load 8 f32 per slot (2 x float4).
// ---------------------------------------------------------------------------
__device__ __forceinline__ void a32_load(const float* src, int lda,
                                         float4 lo[4], float4 hi[4])
{
    const int tid = threadIdx.x;
    #pragma unroll
    for (int q = 0; q < 4; ++q) {
        const int s = q * 256 + tid;
        const int row = s >> 3;
        const int col = ((s & 7) ^ (row & 7)) << 3;
        const float* p = src + (size_t)row * lda + col;
        lo[q] = *(const float4*)p;
        hi[q] = *(const float4*)(p + 4);
    }
}

__device__ __forceinline__ void a32_write(const float4 lo[4], const float4 hi[4],
                                          f16* lds)
{
    const int tid = threadIdx.x;
    #pragma unroll
    for (int q = 0; q < 4; ++q) {
        const int s = q * 256 + tid;
        f16x8 v;
        v[0] = (f16)lo[q].x; v[1] = (f16)lo[q].y;
        v[2] = (f16)lo[q].z; v[3] = (f16)lo[q].w;
        v[4] = (f16)hi[q].x; v[5] = (f16)hi[q].y;
        v[6] = (f16)hi[q].z; v[7] = (f16)hi[q].w;
        *(f16x8*)(lds + (s << 3)) = v;
    }
}

// ---------------------------------------------------------------------------
// GEMM core (proven 2-barrier structure), f16 A via global_load_lds.
// CONV=1: A row base = m0 + (k0>>10) into zero-padded Xt, col = k0&1023.
// ---------------------------------------------------------------------------
template <int CONV>
__device__ __forceinline__ void gemm_core64(
    const f16* __restrict__ A, int lda, int m0,
    const f16* __restrict__ Bt, int ldb, int K,
    f16* Alds, f16* Blds, f32x4 acc[4][4])
{
    const int tid = threadIdx.x;
    const int lid = tid & 63;
    const int wv  = tid >> 6;
    const int wm  = (wv >> 1) * 64;
    const int wn  = (wv & 1) * 64;
    const int g   = lid >> 4;
    const int r15 = lid & 15;

    stage_tile(A + m0 * lda, lda, Alds);
    stage_tile(Bt, ldb, Blds);
    asm volatile("s_waitcnt vmcnt(0)" ::: "memory");
    __builtin_amdgcn_s_barrier();

    for (int k0 = 0; k0 < K; k0 += 64) {
        f16x8 af[2][4], bf[2][4];
        #pragma unroll
        for (int kc = 0; kc < 2; ++kc) {
            #pragma unroll
            for (int mi = 0; mi < 4; ++mi) {
                const int row = wm + mi * 16 + r15;
                af[kc][mi] = *(const f16x8*)(Alds + row * 64 +
                                             (((kc * 4 + g) ^ (row & 7)) << 3));
            }
            #pragma unroll
            for (int nj = 0; nj < 4; ++nj) {
                const int row = wn + nj * 16 + r15;
                bf[kc][nj] = *(const f16x8*)(Blds + row * 64 +
                                             (((kc * 4 + g) ^ (row & 7)) << 3));
            }
        }
        asm volatile("s_waitcnt lgkmcnt(0)" ::: "memory");
        __builtin_amdgcn_sched_barrier(0);
        __builtin_amdgcn_s_barrier();
        const int k1 = k0 + 64;
        if (k1 < K) {
            const f16* Asrc;
            if (CONV) Asrc = A + (m0 + (k1 >> 10)) * lda + (k1 & 1023);
            else      Asrc = A + m0 * lda + k1;
            stage_tile(Asrc, lda, Alds);
            stage_tile(Bt + k1, ldb, Blds);
        }
        __builtin_amdgcn_sched_barrier(0);
        #pragma unroll
        for (int kc = 0; kc < 2; ++kc)
            #pragma unroll
            for (int mi = 0; mi < 4; ++mi)
                #pragma unroll
                for (int nj = 0; nj < 4; ++nj)
                    acc[mi][nj] = __builtin_amdgcn_mfma_f32_16x16x32_f16(
                        af[kc][mi], bf[kc][nj], acc[mi][nj], 0, 0, 0);
        __builtin_amdgcn_sched_barrier(0);
        asm volatile("s_waitcnt vmcnt(0)" ::: "memory");
        __builtin_amdgcn_s_barrier();
    }
}

// ---------------------------------------------------------------------------
// GEMM core with f32 A (fused convert, T14 async split):
//   loop: issue next-A f32 loads -> regs; ds_read cur; lgkm0; barrier;
//         stage next-B (gload_lds); MFMA; cvt+ds_write next-A;
//         vmcnt(0) lgkmcnt(0); barrier.
// ---------------------------------------------------------------------------
__device__ __forceinline__ void gemm_core_a32(
    const float* __restrict__ A, int lda, int m0,
    const f16* __restrict__ Bt, int ldb, int K,
    f16* Alds, f16* Blds, f32x4 acc[4][4])
{
    const int tid = threadIdx.x;
    const int lid = tid & 63;
    const int wv  = tid >> 6;
    const int wm  = (wv >> 1) * 64;
    const int wn  = (wv & 1) * 64;
    const int g   = lid >> 4;
    const int r15 = lid & 15;

    float4 lo[4], hi[4];
    a32_load(A + (size_t)m0 * lda, lda, lo, hi);
    stage_tile(Bt, ldb, Blds);
    a32_write(lo, hi, Alds);                 // waits the loads via data dep
    asm volatile("s_waitcnt vmcnt(0) lgkmcnt(0)" ::: "memory");
    __builtin_amdgcn_s_barrier();

    for (int k0 = 0; k0 < K; k0 += 64) {
        const int k1 = k0 + 64;
        const bool nxt = k1 < K;
        if (nxt) a32_load(A + (size_t)m0 * lda + k1, lda, lo, hi);
        f16x8 af[2][4], bf[2][4];
        #pragma unroll
        for (int kc = 0; kc < 2; ++kc) {
            #pragma unroll
            for (int mi = 0; mi < 4; ++mi) {
                const int row = wm + mi * 16 + r15;
                af[kc][mi] = *(const f16x8*)(Alds + row * 64 +
                                             (((kc * 4 + g) ^ (row & 7)) << 3));
            }
            #pragma unroll
            for (int nj = 0; nj < 4; ++nj) {
                const int row = wn + nj * 16 + r15;
                bf[kc][nj] = *(const f16x8*)(Blds + row * 64 +
                                             (((kc * 4 + g) ^ (row & 7)) << 3));
            }
        }
        asm volatile("s_waitcnt lgkmcnt(0)" ::: "memory");
        __builtin_amdgcn_sched_barrier(0);
        __builtin_amdgcn_s_barrier();        // all waves done reading LDS
        if (nxt) stage_tile(Bt + k1, ldb, Blds);
        __builtin_amdgcn_sched_barrier(0);
        #pragma unroll
        for (int kc = 0; kc < 2; ++kc)
            #pragma unroll
            for (int mi = 0; mi < 4; ++mi)
                #pragma unroll
                for (int nj = 0; nj < 4; ++nj)
                    acc[mi][nj] = __builtin_amdgcn_mfma_f32_16x16x32_f16(
                        af[kc][mi], bf[kc][nj], acc[mi][nj], 0, 0, 0);
        __builtin_amdgcn_sched_barrier(0);
        if (nxt) {
            a32_write(lo, hi, Alds);         // A loads had ds_read+MFMA to land
            asm volatile("s_waitcnt vmcnt(0) lgkmcnt(0)" ::: "memory");
            __builtin_amdgcn_s_barrier();
        }
    }
}

// ---------------------------------------------------------------------------
// Fused transpose+convert for the 4 1024x1024 weights.  grid (32,32,4).
// ---------------------------------------------------------------------------
__global__ __launch_bounds__(256) void k_wtrans(
    const float* __restrict__ WQ, const float* __restrict__ WK,
    const float* __restrict__ WV, const float* __restrict__ Wfc,
    f16* __restrict__ WQt, f16* __restrict__ WKt,
    f16* __restrict__ WVt, f16* __restrict__ WFt)
{
    const int z = blockIdx.z;
    const float* in = z == 0 ? WQ : z == 1 ? WK : z == 2 ? WV : Wfc;
    f16* out = z == 0 ? WQt : z == 1 ? WKt : z == 2 ? WVt : WFt;
    __shared__ float tile[32][33];
    int c0 = blockIdx.x * 32, r0 = blockIdx.y * 32;
    int tx = threadIdx.x, ty = threadIdx.y;
    #pragma unroll
    for (int i = ty; i < 32; i += 8)
        tile[i][tx] = in[(size_t)(r0 + i) * 1024 + c0 + tx];
    __syncthreads();
    #pragma unroll
    for (int i = ty; i < 32; i += 8)
        out[(size_t)(c0 + i) * 1024 + r0 + tx] = (f16)tile[tx][i];
}

// ---------------------------------------------------------------------------
// Fused transpose+convert for conv weights (1024 x 4096).  grid (128,32,2).
// NOTE: must launch AFTER projections — CTk overlays WQt's head (dead then).
// ---------------------------------------------------------------------------
__global__ __launch_bounds__(256) void k_ctrans(
    const float* __restrict__ convq, const float* __restrict__ convk,
    f16* __restrict__ CTq, f16* __restrict__ CTk)
{
    const float* in = blockIdx.z ? convk : convq;
    f16* out = blockIdx.z ? CTk : CTq;
    __shared__ float tile[32][33];
    int c0 = blockIdx.x * 32, r0 = blockIdx.y * 32;
    int tx = threadIdx.x, ty = threadIdx.y;
    #pragma unroll
    for (int i = ty; i < 32; i += 8)
        tile[i][tx] = in[(size_t)(r0 + i) * 4096 + c0 + tx];
    __syncthreads();
    #pragma unroll
    for (int i = ty; i < 32; i += 8)
        out[(size_t)(c0 + i) * 1024 + r0 + tx] = (f16)tile[tx][i];
}

// ---------------------------------------------------------------------------
// Transpose + zero-pad for the conv A-operand.  grid (32,33,8).
// ---------------------------------------------------------------------------
__global__ __launch_bounds__(256) void k_transpose_pad(
    const f16* __restrict__ qx4, const f16* __restrict__ kx4,
    f16* __restrict__ XtQ, f16* __restrict__ XtK)
{
    int z = blockIdx.z, b = z & 3, ten = z >> 2;
    const f16* in = (ten ? kx4 : qx4) + (size_t)b * 1048576;
    f16* out = (ten ? XtK : XtQ) + (size_t)b * XT_BSTRIDE;
    __shared__ f16 tile[32][33];
    int c0 = blockIdx.x * 32;
    int tp0 = blockIdx.y * 32;
    int tx = threadIdx.x, ty = threadIdx.y;
    #pragma unroll
    for (int i = ty; i < 32; i += 8) {
        int t = tp0 + tx - 2;
        tile[i][tx] = (t >= 0 && t < 1024) ? in[(c0 + i) * 1024 + t] : (f16)0.f;
    }
    __syncthreads();
    #pragma unroll
    for (int i = ty; i < 32; i += 8) {
        int tp = tp0 + i;
        if (tp < XT_ROWS) out[tp * 1024 + c0 + tx] = tile[tx][i];
    }
}

// ---------------------------------------------------------------------------
// Projection GEMMs reading f32 Q/K/V DIRECTLY (fused convert in A-staging).
// z=0: q -> qx4 ; z=1: k -> kx4 ; z=2: v -> vT.  XCD-chunked swizzle.
// Coalesced LDS-transpose epilogue.
// ---------------------------------------------------------------------------
__global__ __launch_bounds__(256) void k_gemm_proj(
    const float* __restrict__ Q, const float* __restrict__ K,
    const float* __restrict__ V,
    const f16* __restrict__ WQt, const f16* __restrict__ WKt, const f16* __restrict__ WVt,
    const float* __restrict__ bQ, const float* __restrict__ bK, const float* __restrict__ bV,
    f16* __restrict__ qx4, f16* __restrict__ kx4, f16* __restrict__ vT)
{
    __shared__ __align__(16) f16 smem[16384];
    const int nid = blockIdx.x + blockIdx.y * 8 + blockIdx.z * 256;
    const int wgid = (nid & 7) * 96 + (nid >> 3);      // bijective, 768=8*96
    const int xw = wgid & 7, yw = (wgid >> 3) & 31, z = wgid >> 8;
    const float* A = z == 0 ? Q : z == 1 ? K : V;
    const f16* Bt = z == 0 ? WQt : z == 1 ? WKt : WVt;
    const float* bias = z == 0 ? bQ : z == 1 ? bK : bV;
    f16* dst = z == 0 ? qx4 : z == 1 ? kx4 : vT;
    const int m0 = yw * 128, n0 = xw * 128;
    f32x4 acc[4][4] = {};
    gemm_core_a32(A, 1024, m0, Bt + n0 * 1024, 1024, 1024,
                  smem, smem + 8192, acc);

    const int tid = threadIdx.x, lid = tid & 63, wv = tid >> 6;
    const int wm = (wv >> 1) * 64, g = lid >> 4, r15 = lid & 15;
    f16* T = smem;                        // [128][72], 18432B <= 32KB
    #pragma unroll
    for (int p = 0; p < 2; ++p) {
        __syncthreads();
        if ((wv & 1) == p) {
            #pragma unroll
            for (int nj = 0; nj < 4; ++nj) {
                const int col = n0 + p * 64 + nj * 16 + r15;
                const float bv = bias[col];
                #pragma unroll
                for (int mi = 0; mi < 4; ++mi)
                    #pragma unroll
                    for (int j = 0; j < 4; ++j)
                        T[(wm + mi * 16 + g * 4 + j) * 72 + nj * 16 + r15] =
                            (f16)(acc[mi][nj][j] + bv);
            }
        }
        __syncthreads();
        if (z != 2) {
            const int h = (n0 + p * 64) >> 6;
            #pragma unroll
            for (int q = 0; q < 4; ++q) {
                const int cid = q * 256 + tid;
                const int row = cid >> 3, c = (cid & 7) * 8;
                f16x8 v = *(const f16x8*)(T + row * 72 + c);
                const int grow = m0 + row;
                const int b = grow >> 10, l = grow & 1023;
                *(f16x8*)(dst + b * 1048576 + h * 65536 + l * 64 + c) = v;
            }
        } else {
            const int h = (n0 + p * 64) >> 6;
            #pragma unroll
            for (int q = 0; q < 4; ++q) {
                const int cid = q * 256 + tid;
                const int d = cid >> 4, lc = (cid & 15) * 8;
                f16x8 v;
                #pragma unroll
                for (int e = 0; e < 8; ++e) v[e] = T[(lc + e) * 72 + d];
                const int grow = m0 + lc;
                const int b = grow >> 10, l = grow & 1023;
                *(f16x8*)(dst + b * 1048576 + h * 65536 + d * 1024 + l) = v;
            }
        }
    }
}

// ---------------------------------------------------------------------------
// Fused conv GEMM + residual.  grid (8,8,8) = 512 blocks, z-per-XCD swizzle.
// Epilogue: LDS transpose + coalesced f16x8 residual read/add/write.
// ---------------------------------------------------------------------------
__global__ __launch_bounds__(256) void k_gemm_conv(
    const f16* __restrict__ XtQ, const f16* __restrict__ XtK,
    const f16* __restrict__ CTq, const f16* __restrict__ CTk,
    f16* __restrict__ qx4, f16* __restrict__ kx4,
    const float* __restrict__ wvec)
{
    __shared__ __align__(16) f16 smem[16384];
    const int nid = blockIdx.x + blockIdx.y * 8 + blockIdx.z * 64;
    const int z = nid & 7;                 // XCD-resident (tensor,batch)
    const int inner = nid >> 3;            // 0..63
    const int yw = inner & 7;              // m-tile (fast; A cycles in L2)
    const int xw = inner >> 3;             // n-tile (slow; CT tile hot)
    const int b = z & 3, ten = z >> 2;
    const f16* Xt = (ten ? XtK : XtQ) + (size_t)b * XT_BSTRIDE;
    const f16* CT = ten ? CTk : CTq;
    f16* dst = (ten ? kx4 : qx4) + (size_t)b * 1048576;

    const int flen = (2.f * wvec[0] >= 4.f * wvec[1]) ? 2 : 4;
    const int K = flen << 10;

    const int m0 = yw * 128, n0 = xw * 128;
    f32x4 acc[4][4] = {};
    gemm_core64<1>(Xt, 1024, m0, CT + n0 * 4096, 4096, K,
                   smem, smem + 8192, acc);

    const int tid = threadIdx.x, lid = tid & 63, wv = tid >> 6;
    const int wm = (wv >> 1) * 64, g = lid >> 4, r15 = lid & 15;
    f16* T = smem;
    #pragma unroll
    for (int p = 0; p < 2; ++p) {
        __syncthreads();
        if ((wv & 1) == p) {
            #pragma unroll
            for (int nj = 0; nj < 4; ++nj)
                #pragma unroll
                for (int mi = 0; mi < 4; ++mi)
                    #pragma unroll
                    for (int j = 0; j < 4; ++j)
                        T[(wm + mi * 16 + g * 4 + j) * 72 + nj * 16 + r15] =
                            (f16)acc[mi][nj][j];
        }
        __syncthreads();
        #pragma unroll
        for (int q = 0; q < 4; ++q) {
            const int cid = q * 256 + tid;
            const int row = cid >> 3, c = (cid & 7) * 8;
            f16x8 v = *(const f16x8*)(T + row * 72 + c);
            f16* pdst = dst + (size_t)(m0 + row) * 1024 + n0 + p * 64 + c;
            f16x8 r = *(const f16x8*)pdst;
            f16x8 o2;
            #pragma unroll
            for (int e = 0; e < 8; ++e)
                o2[e] = (f16)((float)v[e] + (float)r[e]);
            *(f16x8*)pdst = o2;
        }
    }
}

// ---------------------------------------------------------------------------
// Flash attention with LDS-staged K/V tiles + double-buffered raw-barrier
// pipeline.  grid (64 bh, 8 qt).  Swapped QK^T; constant-shift exp;
// deferred row-sum; sigma' k-slot bijection on both PV operands.
// ---------------------------------------------------------------------------
__device__ __forceinline__ void attn_tile(
    const f16* KL, const f16* VL,
    const f16* Kn, const f16* Vn, f16* KLn, f16* VLn, bool doStage,
    const f16x8 qf[2][2], f32x4 o[2][4], f32x4 lsum[2], int g, int r15)
{
    f16x8 kf[4][2];
    #pragma unroll
    for (int nj = 0; nj < 4; ++nj)
        #pragma unroll
        for (int kc = 0; kc < 2; ++kc) {
            const int row = nj * 16 + r15;
            kf[nj][kc] = *(const f16x8*)(KL + row * 64 +
                                         (((kc * 4 + g) ^ (row & 7)) << 3));
        }
    f16x4 vlo[4][2], vhi[4][2];
    #pragma unroll
    for (int db = 0; db < 4; ++db)
        #pragma unroll
        for (int ch = 0; ch < 2; ++ch) {
            const int row = db * 16 + r15;
            const int c1 = ch * 4 + (g >> 1);
            const int c2 = c1 + 2;
            const int sub = (g & 1) * 4;
            vlo[db][ch] = *(const f16x4*)(VL + row * 64 +
                                          ((c1 ^ (row & 7)) << 3) + sub);
            vhi[db][ch] = *(const f16x4*)(VL + row * 64 +
                                          ((c2 ^ (row & 7)) << 3) + sub);
        }
    asm volatile("s_waitcnt lgkmcnt(0)" ::: "memory");
    __builtin_amdgcn_sched_barrier(0);
    __builtin_amdgcn_s_barrier();
    if (doStage) {
        stage64(Kn, 64, KLn);
        stage64(Vn, 1024, VLn);
    }
    __builtin_amdgcn_sched_barrier(0);
    f32x4 sacc[2][4] = {};
    #pragma unroll
    for (int nj = 0; nj < 4; ++nj)
        #pragma unroll
        for (int kc = 0; kc < 2; ++kc) {
            sacc[0][nj] = __builtin_amdgcn_mfma_f32_16x16x32_f16(
                kf[nj][kc], qf[0][kc], sacc[0][nj], 0, 0, 0);
            sacc[1][nj] = __builtin_amdgcn_mfma_f32_16x16x32_f16(
                kf[nj][kc], qf[1][kc], sacc[1][nj], 0, 0, 0);
        }
    #pragma unroll
    for (int qh = 0; qh < 2; ++qh) {
        f32x4 pe[4];
        #pragma unroll
        for (int nj = 0; nj < 4; ++nj) {
            #pragma unroll
            for (int j = 0; j < 4; ++j)
                pe[nj][j] = __expf(sacc[qh][nj][j] - 2.0f);
            lsum[qh] += pe[nj];
        }
        f16x8 pb[2];
        #pragma unroll
        for (int ch = 0; ch < 2; ++ch) {
            union { f16x2 h2[4]; f16x8 v8; } u;
            u.h2[0] = pkrtz(pe[2 * ch][0], pe[2 * ch][1]);
            u.h2[1] = pkrtz(pe[2 * ch][2], pe[2 * ch][3]);
            u.h2[2] = pkrtz(pe[2 * ch + 1][0], pe[2 * ch + 1][1]);
            u.h2[3] = pkrtz(pe[2 * ch + 1][2], pe[2 * ch + 1][3]);
            pb[ch] = u.v8;
        }
        #pragma unroll
        for (int db = 0; db < 4; ++db)
            #pragma unroll
            for (int ch = 0; ch < 2; ++ch) {
                union { f16x4 h4[2]; f16x8 v8; } w;
                w.h4[0] = vlo[db][ch];
                w.h4[1] = vhi[db][ch];
                o[qh][db] = __builtin_amdgcn_mfma_f32_16x16x32_f16(
                    w.v8, pb[ch], o[qh][db], 0, 0, 0);
            }
    }
    __builtin_amdgcn_sched_barrier(0);
    asm volatile("s_waitcnt vmcnt(0)" ::: "memory");
    __builtin_amdgcn_s_barrier();
}

__global__ __launch_bounds__(256) void k_attn(
    const f16* __restrict__ qn, const f16* __restrict__ kn,
    const f16* __restrict__ vT, f16* __restrict__ ctx)
{
    __shared__ __align__(16) f16 lds[4][4096];   // K0 V0 K1 V1
    const int bh = blockIdx.x, b = bh >> 4, h = bh & 15;
    const f16* Qp = qn + (size_t)b * 1048576 + h * 65536;
    const f16* Kp = kn + (size_t)b * 1048576 + h * 65536;
    const f16* Vp = vT + (size_t)b * 1048576 + h * 65536;
    const int tid = threadIdx.x, lid = tid & 63, wv = tid >> 6;
    const int g = lid >> 4, r15 = lid & 15;
    const int q0 = blockIdx.y * 128 + wv * 32;

    f16x8 qf[2][2];
    #pragma unroll
    for (int qh = 0; qh < 2; ++qh)
        #pragma unroll
        for (int kc = 0; kc < 2; ++kc) {
            f16x8 t = *(const f16x8*)(Qp + (q0 + qh * 16 + r15) * 64 + kc * 32 + g * 8);
            #pragma unroll
            for (int e = 0; e < 8; ++e) t[e] = t[e] * (f16)0.125f;
            qf[qh][kc] = t;
        }

    f32x4 o[2][4] = {};
    f32x4 lsum[2] = {};

    stage64(Kp, 64, lds[0]);
    stage64(Vp, 1024, lds[1]);
    asm volatile("s_waitcnt vmcnt(0)" ::: "memory");
    __builtin_amdgcn_s_barrier();

    for (int tt = 0; tt < 8; ++tt) {
        const int t1 = 2 * tt + 1;
        attn_tile(lds[0], lds[1], Kp + t1 * 4096, Vp + t1 * 64,
                  lds[2], lds[3], true, qf, o, lsum, g, r15);
        attn_tile(lds[2], lds[3], Kp + (t1 + 1) * 4096, Vp + (t1 + 1) * 64,
                  lds[0], lds[1], tt < 7, qf, o, lsum, g, r15);
    }

    float inv[2];
    #pragma unroll
    for (int qh = 0; qh < 2; ++qh) {
        float lr = lsum[qh][0] + lsum[qh][1] + lsum[qh][2] + lsum[qh][3];
        lr += __shfl_xor(lr, 16);
        lr += __shfl_xor(lr, 32);
        inv[qh] = 1.0f / lr;
    }
    f16* Olds = &lds[0][0] + wv * (32 * 72);
    #pragma unroll
    for (int qh = 0; qh < 2; ++qh)
        #pragma unroll
        for (int db = 0; db < 4; ++db) {
            const int row = qh * 16 + r15, col = db * 16 + g * 4;
            *(f16x2*)(Olds + row * 72 + col) =
                pkrtz(o[qh][db][0] * inv[qh], o[qh][db][1] * inv[qh]);
            *(f16x2*)(Olds + row * 72 + col + 2) =
                pkrtz(o[qh][db][2] * inv[qh], o[qh][db][3] * inv[qh]);
        }
    asm volatile("s_waitcnt lgkmcnt(0)" ::: "memory");
    __builtin_amdgcn_sched_barrier(0);
    #pragma unroll
    for (int p = 0; p < 4; ++p) {
        const int row = p * 8 + (lid >> 3);
        const int c8 = (lid & 7) * 8;
        f16x8 v = *(const f16x8*)(Olds + row * 72 + c8);
        *(f16x8*)(ctx + (size_t)b * 1048576 + (q0 + row) * 1024 + h * 64 + c8) = v;
    }
}

// ---------------------------------------------------------------------------
// Final GEMM: out = ctx @ Wfc + bfc, output FLOAT32.  Chunked XCD swizzle.
// ---------------------------------------------------------------------------
__global__ __launch_bounds__(256) void k_gemm_final(
    const f16* __restrict__ ctx, const f16* __restrict__ WFt,
    const float* __restrict__ bfc, float* __restrict__ out)
{
    __shared__ __align__(16) f16 smem[16384];
    const int nid = blockIdx.x + blockIdx.y * 8;
    const int wgid = (nid & 7) * 32 + (nid >> 3);      // bijective, 256=8*32
    const int xw = wgid & 7, yw = wgid >> 3;
    const int m0 = yw * 128, n0 = xw * 128;
    f32x4 acc[4][4] = {};
    gemm_core64<0>(ctx, 1024, m0, WFt + n0 * 1024, 1024, 1024,
                   smem, smem + 8192, acc);

    const int tid = threadIdx.x, lid = tid & 63, wv = tid >> 6;
    const int wm = (wv >> 1) * 64, wn = (wv & 1) * 64, g = lid >> 4, r15 = lid & 15;
    #pragma unroll
    for (int nj = 0; nj < 4; ++nj) {
        const int col = n0 + wn + nj * 16 + r15;
        const float bv = bfc[col];
        #pragma unroll
        for (int mi = 0; mi < 4; ++mi)
            #pragma unroll
            for (int j = 0; j < 4; ++j) {
                const int row = m0 + wm + mi * 16 + g * 4 + j;
                out[(size_t)row * 1024 + col] = acc[mi][nj][j] + bv;
            }
    }
}

// ---------------------------------------------------------------------------
// Workspace (64 MiB); Qh/Kh/Vh ELIMINATED (proj reads f32 inputs directly):
//   qx4 @0  kx4 @8M  vT @16M  WFt @24M (live: proj..final)
//   WQt @50M  WKt @52M  WVt @54M  CTq @56M
//   XtQ @26M  XtK @34.03M (pad->conv)   CTk @42.05M (overlays WQt head by
//   49KB -> k_ctrans must run AFTER k_gemm_proj)
//   ctxb @26M over dead XtQ (attn->final)
// ---------------------------------------------------------------------------
extern "C" void kernel_launch(void* const* d_in, const int* in_sizes, int n_in,
                              void* d_out, int out_size, void* d_ws, size_t ws_size,
                              hipStream_t stream)
{
    (void)in_sizes; (void)n_in; (void)out_size; (void)ws_size;
    const float* Q     = (const float*)d_in[0];
    const float* K     = (const float*)d_in[1];
    const float* V     = (const float*)d_in[2];
    // d_in[3] = attn_mask (unused by reference)
    const float* WQ    = (const float*)d_in[4];
    const float* bQ    = (const float*)d_in[5];
    const float* WK    = (const float*)d_in[6];
    const float* bK    = (const float*)d_in[7];
    const float* WV    = (const float*)d_in[8];
    const float* bV    = (const float*)d_in[9];
    const float* Wfc   = (const float*)d_in[10];
    const float* bfc   = (const float*)d_in[11];
    const float* convq = (const float*)d_in[12];
    const float* convk = (const float*)d_in[13];
    const float* w     = (const float*)d_in[14];

    char* ws = (char*)d_ws;
    f16* qx4   = (f16*)(ws + 0);
    f16* kx4   = (f16*)(ws + 8388608);
    f16* vT    = (f16*)(ws + 16777216);
    f16* WFt   = (f16*)(ws + 25165824);
    f16* WQt   = (f16*)(ws + 52428800);
    f16* WKt   = (f16*)(ws + 54525952);
    f16* WVt   = (f16*)(ws + 56623104);
    f16* CTq   = (f16*)(ws + 58720256);
    f16* XtQ   = (f16*)(ws + 27262976);
    f16* XtK   = (f16*)(ws + 35676160);
    f16* CTk   = (f16*)(ws + 44089344);  // overlays WQt head - AFTER proj!
    f16* ctxb  = (f16*)(ws + 27262976);  // over dead XtQ (attn->final)

    dim3 b256(256), bT(32, 8);

    // 1) weight transposes for projections
    k_wtrans<<<dim3(32, 32, 4), bT, 0, stream>>>(WQ, WK, WV, Wfc,
                                                 WQt, WKt, WVt, WFt);
    // 2) projections (read f32 Q/K/V directly; fused convert in staging)
    k_gemm_proj<<<dim3(8, 32, 3), b256, 0, stream>>>(Q, K, V, WQt, WKt, WVt,
                                                     bQ, bK, bV, qx4, kx4, vT);
    // 3) conv A-operand: transpose + zero-pad
    k_transpose_pad<<<dim3(32, 33, 8), bT, 0, stream>>>(qx4, kx4, XtQ, XtK);
    // 4) conv weight transposes (CTk over dead WQt head -- after proj)
    k_ctrans<<<dim3(128, 32, 2), bT, 0, stream>>>(convq, convk, CTq, CTk);
    // 5) fused conv GEMM + residual (z-per-XCD swizzle, coalesced epilogue)
    k_gemm_conv<<<dim3(8, 8, 8), b256, 0, stream>>>(XtQ, XtK, CTq, CTk,
                                                    qx4, kx4, w);
    // 6) flash attention -> ctx (LDS-staged K/V; XCD-friendly grid x=bh)
    k_attn<<<dim3(64, 8), b256, 0, stream>>>(qx4, kx4, vT, ctxb);
    // 7) final projection -> f32 output (chunked swizzle)
    k_gemm_final<<<dim3(8, 32), b256, 0, stream>>>(ctxb, WFt, bfc, (float*)d_out);
}

// Round 17
// 175.414 us; speedup vs baseline: 1.1018x; 1.1018x over previous
//
#include <hip/hip_runtime.h>
#include <hip/hip_bf16.h>

typedef _Float16 f16;
typedef _Float16 f16x2 __attribute__((ext_vector_type(2)));
typedef _Float16 f16x4 __attribute__((ext_vector_type(4)));
typedef _Float16 f16x8 __attribute__((ext_vector_type(8)));
typedef float f32x4 __attribute__((ext_vector_type(4)));

// cvt_pkrtz returns __fp16 ext_vector(2); re-cast to our f16x2 (same bits).
__device__ __forceinline__ f16x2 pkrtz(float a, float b) {
    auto r = __builtin_amdgcn_cvt_pkrtz(a, b);
    f16x2 o; o[0] = (f16)r[0]; o[1] = (f16)r[1];
    return o;
}

#define XT_ROWS 1027
#define XT_BSTRIDE (XT_ROWS * 1024)   // elems per batch

// ---------------------------------------------------------------------------
// global -> LDS direct (16B per lane, wave-uniform LDS base + lane*16)
// ---------------------------------------------------------------------------
__device__ __forceinline__ void gload16(const f16* g, f16* l) {
    __builtin_amdgcn_global_load_lds(
        (const __attribute__((address_space(1))) void*)g,
        (__attribute__((address_space(3))) void*)l, 16, 0, 0);
}

// ---------------------------------------------------------------------------
// Stage a 128x64 f16 tile (16KB).  XOR-swizzle on SOURCE col; same XOR on
// the read side (involution) -> conflict-free ds_read_b128.
// ---------------------------------------------------------------------------
__device__ __forceinline__ void stage_tile(const f16* src, int ld, f16* lds)
{
    const int tid = threadIdx.x;
    const int w512 = (tid >> 6) << 9;          // wave base (f16 elems)
    #pragma unroll
    for (int q = 0; q < 4; ++q) {
        const int s = q * 256 + tid;           // 16B slot id, 0..1023
        const int row = s >> 3;
        const int col = ((s & 7) ^ (row & 7)) << 3;
        gload16(src + row * ld + col, lds + (q << 11) + w512);
    }
}

// ---------------------------------------------------------------------------
// Stage a 64x64 f16 tile (8KB) the same way (512 slots, 2 per thread).
// ---------------------------------------------------------------------------
__device__ __forceinline__ void stage64(const f16* src, int ld, f16* lds)
{
    const int tid = threadIdx.x;
    const int w512 = (tid >> 6) << 9;
    #pragma unroll
    for (int q = 0; q < 2; ++q) {
        const int s = q * 256 + tid;           // 16B slot id, 0..511
        const int row = s >> 3;
        const int col = ((s & 7) ^ (row & 7)) << 3;
        gload16(src + row * ld + col, lds + (q << 11) + w512);
    }
}

// ---------------------------------------------------------------------------
// GEMM core 128x128 (proven 2-barrier structure).
// CONV=1: A row base = m0 + (k0>>10) into zero-padded Xt, col = k0&1023.
// ---------------------------------------------------------------------------
template <int CONV>
__device__ __forceinline__ void gemm_core64(
    const f16* __restrict__ A, int lda, int m0,
    const f16* __restrict__ Bt, int ldb, int K,
    f16* Alds, f16* Blds, f32x4 acc[4][4])
{
    const int tid = threadIdx.x;
    const int lid = tid & 63;
    const int wv  = tid >> 6;
    const int wm  = (wv >> 1) * 64;
    const int wn  = (wv & 1) * 64;
    const int g   = lid >> 4;
    const int r15 = lid & 15;

    stage_tile(A + m0 * lda, lda, Alds);
    stage_tile(Bt, ldb, Blds);
    asm volatile("s_waitcnt vmcnt(0)" ::: "memory");
    __builtin_amdgcn_s_barrier();

    for (int k0 = 0; k0 < K; k0 += 64) {
        f16x8 af[2][4], bf[2][4];
        #pragma unroll
        for (int kc = 0; kc < 2; ++kc) {
            #pragma unroll
            for (int mi = 0; mi < 4; ++mi) {
                const int row = wm + mi * 16 + r15;
                af[kc][mi] = *(const f16x8*)(Alds + row * 64 +
                                             (((kc * 4 + g) ^ (row & 7)) << 3));
            }
            #pragma unroll
            for (int nj = 0; nj < 4; ++nj) {
                const int row = wn + nj * 16 + r15;
                bf[kc][nj] = *(const f16x8*)(Blds + row * 64 +
                                             (((kc * 4 + g) ^ (row & 7)) << 3));
            }
        }
        asm volatile("s_waitcnt lgkmcnt(0)" ::: "memory");
        __builtin_amdgcn_sched_barrier(0);
        __builtin_amdgcn_s_barrier();
        const int k1 = k0 + 64;
        if (k1 < K) {
            const f16* Asrc;
            if (CONV) Asrc = A + (m0 + (k1 >> 10)) * lda + (k1 & 1023);
            else      Asrc = A + m0 * lda + k1;
            stage_tile(Asrc, lda, Alds);
            stage_tile(Bt + k1, ldb, Blds);
        }
        __builtin_amdgcn_sched_barrier(0);
        #pragma unroll
        for (int kc = 0; kc < 2; ++kc)
            #pragma unroll
            for (int mi = 0; mi < 4; ++mi)
                #pragma unroll
                for (int nj = 0; nj < 4; ++nj)
                    acc[mi][nj] = __builtin_amdgcn_mfma_f32_16x16x32_f16(
                        af[kc][mi], bf[kc][nj], acc[mi][nj], 0, 0, 0);
        __builtin_amdgcn_sched_barrier(0);
        asm volatile("s_waitcnt vmcnt(0)" ::: "memory");
        __builtin_amdgcn_s_barrier();
    }
}

// ---------------------------------------------------------------------------
// GEMM core 64x128 (small tile, 24KB LDS -> 2x blocks/CU for TLP hiding).
// Waves 2x2: wave tile 32x64.  acc[2][4].
// ---------------------------------------------------------------------------
__device__ __forceinline__ void gemm_core_s(
    const f16* __restrict__ A, int lda, int m0,
    const f16* __restrict__ Bt, int ldb, int K,
    f16* Alds, f16* Blds, f32x4 acc[2][4])
{
    const int tid = threadIdx.x;
    const int lid = tid & 63;
    const int wv  = tid >> 6;
    const int wm  = (wv >> 1) * 32;
    const int wn  = (wv & 1) * 64;
    const int g   = lid >> 4;
    const int r15 = lid & 15;

    stage64(A + m0 * lda, lda, Alds);
    stage_tile(Bt, ldb, Blds);
    asm volatile("s_waitcnt vmcnt(0)" ::: "memory");
    __builtin_amdgcn_s_barrier();

    for (int k0 = 0; k0 < K; k0 += 64) {
        f16x8 af[2][2], bf[2][4];
        #pragma unroll
        for (int kc = 0; kc < 2; ++kc) {
            #pragma unroll
            for (int mi = 0; mi < 2; ++mi) {
                const int row = wm + mi * 16 + r15;
                af[kc][mi] = *(const f16x8*)(Alds + row * 64 +
                                             (((kc * 4 + g) ^ (row & 7)) << 3));
            }
            #pragma unroll
            for (int nj = 0; nj < 4; ++nj) {
                const int row = wn + nj * 16 + r15;
                bf[kc][nj] = *(const f16x8*)(Blds + row * 64 +
                                             (((kc * 4 + g) ^ (row & 7)) << 3));
            }
        }
        asm volatile("s_waitcnt lgkmcnt(0)" ::: "memory");
        __builtin_amdgcn_sched_barrier(0);
        __builtin_amdgcn_s_barrier();
        const int k1 = k0 + 64;
        if (k1 < K) {
            stage64(A + m0 * lda + k1, lda, Alds);
            stage_tile(Bt + k1, ldb, Blds);
        }
        __builtin_amdgcn_sched_barrier(0);
        #pragma unroll
        for (int kc = 0; kc < 2; ++kc)
            #pragma unroll
            for (int mi = 0; mi < 2; ++mi)
                #pragma unroll
                for (int nj = 0; nj < 4; ++nj)
                    acc[mi][nj] = __builtin_amdgcn_mfma_f32_16x16x32_f16(
                        af[kc][mi], bf[kc][nj], acc[mi][nj], 0, 0, 0);
        __builtin_amdgcn_sched_barrier(0);
        asm volatile("s_waitcnt vmcnt(0)" ::: "memory");
        __builtin_amdgcn_s_barrier();
    }
}

// ---------------------------------------------------------------------------
// Fused fp32 -> fp16 convert for Q,K,V (grid 3*4096 blocks).
// ---------------------------------------------------------------------------
__global__ __launch_bounds__(256) void k_cvt_all(
    const float* __restrict__ Q, const float* __restrict__ K,
    const float* __restrict__ V, f16* __restrict__ Qh,
    f16* __restrict__ Kh, f16* __restrict__ Vh)
{
    const int bid = blockIdx.x;
    const int which = bid >> 12;
    const int i = (bid & 4095) * 256 + threadIdx.x;
    const float* in = which == 0 ? Q : which == 1 ? K : V;
    f16* out = which == 0 ? Qh : which == 1 ? Kh : Vh;
    float4 v = ((const float4*)in)[i];
    f16x4 o;
    o[0] = (f16)v.x; o[1] = (f16)v.y; o[2] = (f16)v.z; o[3] = (f16)v.w;
    ((f16x4*)out)[i] = o;
}

// ---------------------------------------------------------------------------
// Fused transpose+convert for the 4 1024x1024 weights.  grid (32,32,4).
// ---------------------------------------------------------------------------
__global__ __launch_bounds__(256) void k_wtrans(
    const float* __restrict__ WQ, const float* __restrict__ WK,
    const float* __restrict__ WV, const float* __restrict__ Wfc,
    f16* __restrict__ WQt, f16* __restrict__ WKt,
    f16* __restrict__ WVt, f16* __restrict__ WFt)
{
    const int z = blockIdx.z;
    const float* in = z == 0 ? WQ : z == 1 ? WK : z == 2 ? WV : Wfc;
    f16* out = z == 0 ? WQt : z == 1 ? WKt : z == 2 ? WVt : WFt;
    __shared__ float tile[32][33];
    int c0 = blockIdx.x * 32, r0 = blockIdx.y * 32;
    int tx = threadIdx.x, ty = threadIdx.y;
    #pragma unroll
    for (int i = ty; i < 32; i += 8)
        tile[i][tx] = in[(size_t)(r0 + i) * 1024 + c0 + tx];
    __syncthreads();
    #pragma unroll
    for (int i = ty; i < 32; i += 8)
        out[(size_t)(c0 + i) * 1024 + r0 + tx] = (f16)tile[tx][i];
}

// ---------------------------------------------------------------------------
// Fused transpose+convert for conv weights (1024 x 4096).  grid (128,32,2).
// NOTE: must launch AFTER projections — CTk overlays dead Vh/WQt.
// ---------------------------------------------------------------------------
__global__ __launch_bounds__(256) void k_ctrans(
    const float* __restrict__ convq, const float* __restrict__ convk,
    f16* __restrict__ CTq, f16* __restrict__ CTk)
{
    const float* in = blockIdx.z ? convk : convq;
    f16* out = blockIdx.z ? CTk : CTq;
    __shared__ float tile[32][33];
    int c0 = blockIdx.x * 32, r0 = blockIdx.y * 32;
    int tx = threadIdx.x, ty = threadIdx.y;
    #pragma unroll
    for (int i = ty; i < 32; i += 8)
        tile[i][tx] = in[(size_t)(r0 + i) * 4096 + c0 + tx];
    __syncthreads();
    #pragma unroll
    for (int i = ty; i < 32; i += 8)
        out[(size_t)(c0 + i) * 1024 + r0 + tx] = (f16)tile[tx][i];
}

// ---------------------------------------------------------------------------
// Transpose + zero-pad for the conv A-operand.  grid (32,33,8).
// ---------------------------------------------------------------------------
__global__ __launch_bounds__(256) void k_transpose_pad(
    const f16* __restrict__ qx4, const f16* __restrict__ kx4,
    f16* __restrict__ XtQ, f16* __restrict__ XtK)
{
    int z = blockIdx.z, b = z & 3, ten = z >> 2;
    const f16* in = (ten ? kx4 : qx4) + (size_t)b * 1048576;
    f16* out = (ten ? XtK : XtQ) + (size_t)b * XT_BSTRIDE;
    __shared__ f16 tile[32][33];
    int c0 = blockIdx.x * 32;
    int tp0 = blockIdx.y * 32;
    int tx = threadIdx.x, ty = threadIdx.y;
    #pragma unroll
    for (int i = ty; i < 32; i += 8) {
        int t = tp0 + tx - 2;
        tile[i][tx] = (t >= 0 && t < 1024) ? in[(c0 + i) * 1024 + t] : (f16)0.f;
    }
    __syncthreads();
    #pragma unroll
    for (int i = ty; i < 32; i += 8) {
        int tp = tp0 + i;
        if (tp < XT_ROWS) out[tp * 1024 + c0 + tx] = tile[tx][i];
    }
}

// ---------------------------------------------------------------------------
// Projection GEMMs, 64x128 tiles (grid 1536 = 6 blocks/CU for TLP hiding).
// z=0: q -> qx4 ; z=1: k -> kx4 ; z=2: v -> vT.  XCD-chunked swizzle
// (1536 = 8*192).  Coalesced LDS-transpose epilogue ([64][72] T tile).
// ---------------------------------------------------------------------------
__global__ __launch_bounds__(256) void k_gemm_proj(
    const f16* __restrict__ Qh, const f16* __restrict__ Kh, const f16* __restrict__ Vh,
    const f16* __restrict__ WQt, const f16* __restrict__ WKt, const f16* __restrict__ WVt,
    const float* __restrict__ bQ, const float* __restrict__ bK, const float* __restrict__ bV,
    f16* __restrict__ qx4, f16* __restrict__ kx4, f16* __restrict__ vT)
{
    __shared__ __align__(16) f16 smem[12288];   // A 8KB @0, B 16KB @4096
    const int nid = blockIdx.x + blockIdx.y * 8 + blockIdx.z * 512;
    const int wgid = (nid & 7) * 192 + (nid >> 3);     // bijective, 1536=8*192
    const int z = wgid >> 9, rem = wgid & 511;
    const int yw = rem & 63, xw = rem >> 6;
    const f16* A  = z == 0 ? Qh : z == 1 ? Kh : Vh;
    const f16* Bt = z == 0 ? WQt : z == 1 ? WKt : WVt;
    const float* bias = z == 0 ? bQ : z == 1 ? bK : bV;
    f16* dst = z == 0 ? qx4 : z == 1 ? kx4 : vT;
    const int m0 = yw * 64, n0 = xw * 128;
    f32x4 acc[2][4] = {};
    gemm_core_s(A, 1024, m0, Bt + n0 * 1024, 1024, 1024,
                smem, smem + 4096, acc);

    const int tid = threadIdx.x, lid = tid & 63, wv = tid >> 6;
    const int wm = (wv >> 1) * 32, g = lid >> 4, r15 = lid & 15;
    f16* T = smem;                        // [64][72] = 9216B
    #pragma unroll
    for (int p = 0; p < 2; ++p) {
        __syncthreads();
        if ((wv & 1) == p) {
            #pragma unroll
            for (int nj = 0; nj < 4; ++nj) {
                const int col = n0 + p * 64 + nj * 16 + r15;
                const float bv = bias[col];
                #pragma unroll
                for (int mi = 0; mi < 2; ++mi)
                    #pragma unroll
                    for (int j = 0; j < 4; ++j)
                        T[(wm + mi * 16 + g * 4 + j) * 72 + nj * 16 + r15] =
                            (f16)(acc[mi][nj][j] + bv);
            }
        }
        __syncthreads();
        const int h = (n0 + p * 64) >> 6;
        if (z != 2) {
            #pragma unroll
            for (int q = 0; q < 2; ++q) {
                const int cid = q * 256 + tid;        // 0..511
                const int row = cid >> 3, c = (cid & 7) * 8;
                f16x8 v = *(const f16x8*)(T + row * 72 + c);
                const int grow = m0 + row;
                const int b = grow >> 10, l = grow & 1023;
                *(f16x8*)(dst + b * 1048576 + h * 65536 + l * 64 + c) = v;
            }
        } else {
            const int b = m0 >> 10, l0 = m0 & 1023;
            #pragma unroll
            for (int q = 0; q < 2; ++q) {
                const int cid = q * 256 + tid;        // 0..511
                const int d = cid >> 3, lc = (cid & 7) * 8;
                f16x8 v;
                #pragma unroll
                for (int e = 0; e < 8; ++e) v[e] = T[(lc + e) * 72 + d];
                *(f16x8*)(dst + b * 1048576 + h * 65536 + d * 1024 + l0 + lc) = v;
            }
        }
    }
}

// ---------------------------------------------------------------------------
// Fused conv GEMM + residual.  grid (8,8,8) = 512 blocks, z-per-XCD swizzle.
// Epilogue: LDS transpose + coalesced f16x8 residual read/add/write.
// ---------------------------------------------------------------------------
__global__ __launch_bounds__(256) void k_gemm_conv(
    const f16* __restrict__ XtQ, const f16* __restrict__ XtK,
    const f16* __restrict__ CTq, const f16* __restrict__ CTk,
    f16* __restrict__ qx4, f16* __restrict__ kx4,
    const float* __restrict__ wvec)
{
    __shared__ __align__(16) f16 smem[16384];
    const int nid = blockIdx.x + blockIdx.y * 8 + blockIdx.z * 64;
    const int z = nid & 7;                 // XCD-resident (tensor,batch)
    const int inner = nid >> 3;            // 0..63
    const int yw = inner & 7;              // m-tile (fast; A cycles in L2)
    const int xw = inner >> 3;             // n-tile (slow; CT tile hot)
    const int b = z & 3, ten = z >> 2;
    const f16* Xt = (ten ? XtK : XtQ) + (size_t)b * XT_BSTRIDE;
    const f16* CT = ten ? CTk : CTq;
    f16* dst = (ten ? kx4 : qx4) + (size_t)b * 1048576;

    const int flen = (2.f * wvec[0] >= 4.f * wvec[1]) ? 2 : 4;
    const int K = flen << 10;

    const int m0 = yw * 128, n0 = xw * 128;
    f32x4 acc[4][4] = {};
    gemm_core64<1>(Xt, 1024, m0, CT + n0 * 4096, 4096, K,
                   smem, smem + 8192, acc);

    const int tid = threadIdx.x, lid = tid & 63, wv = tid >> 6;
    const int wm = (wv >> 1) * 64, g = lid >> 4, r15 = lid & 15;
    f16* T = smem;
    #pragma unroll
    for (int p = 0; p < 2; ++p) {
        __syncthreads();
        if ((wv & 1) == p) {
            #pragma unroll
            for (int nj = 0; nj < 4; ++nj)
                #pragma unroll
                for (int mi = 0; mi < 4; ++mi)
                    #pragma unroll
                    for (int j = 0; j < 4; ++j)
                        T[(wm + mi * 16 + g * 4 + j) * 72 + nj * 16 + r15] =
                            (f16)acc[mi][nj][j];
        }
        __syncthreads();
        #pragma unroll
        for (int q = 0; q < 4; ++q) {
            const int cid = q * 256 + tid;
            const int row = cid >> 3, c = (cid & 7) * 8;
            f16x8 v = *(const f16x8*)(T + row * 72 + c);
            f16* pdst = dst + (size_t)(m0 + row) * 1024 + n0 + p * 64 + c;
            f16x8 r = *(const f16x8*)pdst;
            f16x8 o2;
            #pragma unroll
            for (int e = 0; e < 8; ++e)
                o2[e] = (f16)((float)v[e] + (float)r[e]);
            *(f16x8*)pdst = o2;
        }
    }
}

// ---------------------------------------------------------------------------
// Flash attention with LDS-staged K/V tiles + double-buffered raw-barrier
// pipeline.  grid (64 bh, 8 qt).  Swapped QK^T; constant-shift exp;
// deferred row-sum; sigma' k-slot bijection on both PV operands.
// ---------------------------------------------------------------------------
__device__ __forceinline__ void attn_tile(
    const f16* KL, const f16* VL,
    const f16* Kn, const f16* Vn, f16* KLn, f16* VLn, bool doStage,
    const f16x8 qf[2][2], f32x4 o[2][4], f32x4 lsum[2], int g, int r15)
{
    f16x8 kf[4][2];
    #pragma unroll
    for (int nj = 0; nj < 4; ++nj)
        #pragma unroll
        for (int kc = 0; kc < 2; ++kc) {
            const int row = nj * 16 + r15;
            kf[nj][kc] = *(const f16x8*)(KL + row * 64 +
                                         (((kc * 4 + g) ^ (row & 7)) << 3));
        }
    f16x4 vlo[4][2], vhi[4][2];
    #pragma unroll
    for (int db = 0; db < 4; ++db)
        #pragma unroll
        for (int ch = 0; ch < 2; ++ch) {
            const int row = db * 16 + r15;
            const int c1 = ch * 4 + (g >> 1);
            const int c2 = c1 + 2;
            const int sub = (g & 1) * 4;
            vlo[db][ch] = *(const f16x4*)(VL + row * 64 +
                                          ((c1 ^ (row & 7)) << 3) + sub);
            vhi[db][ch] = *(const f16x4*)(VL + row * 64 +
                                          ((c2 ^ (row & 7)) << 3) + sub);
        }
    asm volatile("s_waitcnt lgkmcnt(0)" ::: "memory");
    __builtin_amdgcn_sched_barrier(0);
    __builtin_amdgcn_s_barrier();
    if (doStage) {
        stage64(Kn, 64, KLn);
        stage64(Vn, 1024, VLn);
    }
    __builtin_amdgcn_sched_barrier(0);
    f32x4 sacc[2][4] = {};
    #pragma unroll
    for (int nj = 0; nj < 4; ++nj)
        #pragma unroll
        for (int kc = 0; kc < 2; ++kc) {
            sacc[0][nj] = __builtin_amdgcn_mfma_f32_16x16x32_f16(
                kf[nj][kc], qf[0][kc], sacc[0][nj], 0, 0, 0);
            sacc[1][nj] = __builtin_amdgcn_mfma_f32_16x16x32_f16(
                kf[nj][kc], qf[1][kc], sacc[1][nj], 0, 0, 0);
        }
    #pragma unroll
    for (int qh = 0; qh < 2; ++qh) {
        f32x4 pe[4];
        #pragma unroll
        for (int nj = 0; nj < 4; ++nj) {
            #pragma unroll
            for (int j = 0; j < 4; ++j)
                pe[nj][j] = __expf(sacc[qh][nj][j] - 2.0f);
            lsum[qh] += pe[nj];
        }
        f16x8 pb[2];
        #pragma unroll
        for (int ch = 0; ch < 2; ++ch) {
            union { f16x2 h2[4]; f16x8 v8; } u;
            u.h2[0] = pkrtz(pe[2 * ch][0], pe[2 * ch][1]);
            u.h2[1] = pkrtz(pe[2 * ch][2], pe[2 * ch][3]);
            u.h2[2] = pkrtz(pe[2 * ch + 1][0], pe[2 * ch + 1][1]);
            u.h2[3] = pkrtz(pe[2 * ch + 1][2], pe[2 * ch + 1][3]);
            pb[ch] = u.v8;
        }
        #pragma unroll
        for (int db = 0; db < 4; ++db)
            #pragma unroll
            for (int ch = 0; ch < 2; ++ch) {
                union { f16x4 h4[2]; f16x8 v8; } w;
                w.h4[0] = vlo[db][ch];
                w.h4[1] = vhi[db][ch];
                o[qh][db] = __builtin_amdgcn_mfma_f32_16x16x32_f16(
                    w.v8, pb[ch], o[qh][db], 0, 0, 0);
            }
    }
    __builtin_amdgcn_sched_barrier(0);
    asm volatile("s_waitcnt vmcnt(0)" ::: "memory");
    __builtin_amdgcn_s_barrier();
}

__global__ __launch_bounds__(256) void k_attn(
    const f16* __restrict__ qn, const f16* __restrict__ kn,
    const f16* __restrict__ vT, f16* __restrict__ ctx)
{
    __shared__ __align__(16) f16 lds[4][4096];   // K0 V0 K1 V1
    const int bh = blockIdx.x, b = bh >> 4, h = bh & 15;
    const f16* Qp = qn + (size_t)b * 1048576 + h * 65536;
    const f16* Kp = kn + (size_t)b * 1048576 + h * 65536;
    const f16* Vp = vT + (size_t)b * 1048576 + h * 65536;
    const int tid = threadIdx.x, lid = tid & 63, wv = tid >> 6;
    const int g = lid >> 4, r15 = lid & 15;
    const int q0 = blockIdx.y * 128 + wv * 32;

    f16x8 qf[2][2];
    #pragma unroll
    for (int qh = 0; qh < 2; ++qh)
        #pragma unroll
        for (int kc = 0; kc < 2; ++kc) {
            f16x8 t = *(const f16x8*)(Qp + (q0 + qh * 16 + r15) * 64 + kc * 32 + g * 8);
            #pragma unroll
            for (int e = 0; e < 8; ++e) t[e] = t[e] * (f16)0.125f;
            qf[qh][kc] = t;
        }

    f32x4 o[2][4] = {};
    f32x4 lsum[2] = {};

    stage64(Kp, 64, lds[0]);
    stage64(Vp, 1024, lds[1]);
    asm volatile("s_waitcnt vmcnt(0)" ::: "memory");
    __builtin_amdgcn_s_barrier();

    for (int tt = 0; tt < 8; ++tt) {
        const int t1 = 2 * tt + 1;
        attn_tile(lds[0], lds[1], Kp + t1 * 4096, Vp + t1 * 64,
                  lds[2], lds[3], true, qf, o, lsum, g, r15);
        attn_tile(lds[2], lds[3], Kp + (t1 + 1) * 4096, Vp + (t1 + 1) * 64,
                  lds[0], lds[1], tt < 7, qf, o, lsum, g, r15);
    }

    float inv[2];
    #pragma unroll
    for (int qh = 0; qh < 2; ++qh) {
        float lr = lsum[qh][0] + lsum[qh][1] + lsum[qh][2] + lsum[qh][3];
        lr += __shfl_xor(lr, 16);
        lr += __shfl_xor(lr, 32);
        inv[qh] = 1.0f / lr;
    }
    f16* Olds = &lds[0][0] + wv * (32 * 72);
    #pragma unroll
    for (int qh = 0; qh < 2; ++qh)
        #pragma unroll
        for (int db = 0; db < 4; ++db) {
            const int row = qh * 16 + r15, col = db * 16 + g * 4;
            *(f16x2*)(Olds + row * 72 + col) =
                pkrtz(o[qh][db][0] * inv[qh], o[qh][db][1] * inv[qh]);
            *(f16x2*)(Olds + row * 72 + col + 2) =
                pkrtz(o[qh][db][2] * inv[qh], o[qh][db][3] * inv[qh]);
        }
    asm volatile("s_waitcnt lgkmcnt(0)" ::: "memory");
    __builtin_amdgcn_sched_barrier(0);
    #pragma unroll
    for (int p = 0; p < 4; ++p) {
        const int row = p * 8 + (lid >> 3);
        const int c8 = (lid & 7) * 8;
        f16x8 v = *(const f16x8*)(Olds + row * 72 + c8);
        *(f16x8*)(ctx + (size_t)b * 1048576 + (q0 + row) * 1024 + h * 64 + c8) = v;
    }
}

// ---------------------------------------------------------------------------
// Final GEMM: out = ctx @ Wfc + bfc, output FLOAT32.  Chunked XCD swizzle.
// ---------------------------------------------------------------------------
__global__ __launch_bounds__(256) void k_gemm_final(
    const f16* __restrict__ ctx, const f16* __restrict__ WFt,
    const float* __restrict__ bfc, float* __restrict__ out)
{
    __shared__ __align__(16) f16 smem[16384];
    const int nid = blockIdx.x + blockIdx.y * 8;
    const int wgid = (nid & 7) * 32 + (nid >> 3);      // bijective, 256=8*32
    const int xw = wgid & 7, yw = wgid >> 3;
    const int m0 = yw * 128, n0 = xw * 128;
    f32x4 acc[4][4] = {};
    gemm_core64<0>(ctx, 1024, m0, WFt + n0 * 1024, 1024, 1024,
                   smem, smem + 8192, acc);

    const int tid = threadIdx.x, lid = tid & 63, wv = tid >> 6;
    const int wm = (wv >> 1) * 64, wn = (wv & 1) * 64, g = lid >> 4, r15 = lid & 15;
    #pragma unroll
    for (int nj = 0; nj < 4; ++nj) {
        const int col = n0 + wn + nj * 16 + r15;
        const float bv = bfc[col];
        #pragma unroll
        for (int mi = 0; mi < 4; ++mi)
            #pragma unroll
            for (int j = 0; j < 4; ++j) {
                const int row = m0 + wm + mi * 16 + g * 4 + j;
                out[(size_t)row * 1024 + col] = acc[mi][nj][j] + bv;
            }
    }
}

// ---------------------------------------------------------------------------
// Workspace (64 MiB), round-15 layout:
//   qx4 @0  kx4 @8M  vT @16M  WFt @24M (live: proj..final)
//   Qh @26M  Kh @34M  Vh @42M  WQt @50M  WKt @52M  WVt @54M  CTq @56M
//   After proj: XtQ @26M  XtK @34.03M  CTk @42.05M (over dead Vh/WQt)
//   After conv: ctxb @26M over dead XtQ (attn -> final)
//   ORDER: k_ctrans AFTER k_gemm_proj (CTk overlays Vh/WQt).
// ---------------------------------------------------------------------------
extern "C" void kernel_launch(void* const* d_in, const int* in_sizes, int n_in,
                              void* d_out, int out_size, void* d_ws, size_t ws_size,
                              hipStream_t stream)
{
    (void)in_sizes; (void)n_in; (void)out_size; (void)ws_size;
    const float* Q     = (const float*)d_in[0];
    const float* K     = (const float*)d_in[1];
    const float* V     = (const float*)d_in[2];
    // d_in[3] = attn_mask (unused by reference)
    const float* WQ    = (const float*)d_in[4];
    const float* bQ    = (const float*)d_in[5];
    const float* WK    = (const float*)d_in[6];
    const float* bK    = (const float*)d_in[7];
    const float* WV    = (const float*)d_in[8];
    const float* bV    = (const float*)d_in[9];
    const float* Wfc   = (const float*)d_in[10];
    const float* bfc   = (const float*)d_in[11];
    const float* convq = (const float*)d_in[12];
    const float* convk = (const float*)d_in[13];
    const float* w     = (const float*)d_in[14];

    char* ws = (char*)d_ws;
    f16* qx4   = (f16*)(ws + 0);
    f16* kx4   = (f16*)(ws + 8388608);
    f16* vT    = (f16*)(ws + 16777216);
    f16* WFt   = (f16*)(ws + 25165824);
    f16* Qh    = (f16*)(ws + 27262976);
    f16* Kh    = (f16*)(ws + 35651584);
    f16* Vh    = (f16*)(ws + 44040192);
    f16* WQt   = (f16*)(ws + 52428800);
    f16* WKt   = (f16*)(ws + 54525952);
    f16* WVt   = (f16*)(ws + 56623104);
    f16* CTq   = (f16*)(ws + 58720256);
    f16* XtQ   = (f16*)(ws + 27262976);  // over dead Qh (+Kh head)
    f16* XtK   = (f16*)(ws + 35676160);  // over dead Kh (+Vh head)
    f16* CTk   = (f16*)(ws + 44089344);  // over dead Vh (+WQt head) - AFTER proj!
    f16* ctxb  = (f16*)(ws + 27262976);  // over dead XtQ (attn->final)

    dim3 b256(256), bT(32, 8);

    // 1) fp32 -> fp16 inputs
    k_cvt_all<<<12288, b256, 0, stream>>>(Q, K, V, Qh, Kh, Vh);
    // 2) weight transposes for projections
    k_wtrans<<<dim3(32, 32, 4), bT, 0, stream>>>(WQ, WK, WV, Wfc,
                                                 WQt, WKt, WVt, WFt);
    // 3) projections (64x128 tiles, 1536 blocks = 6/CU)
    k_gemm_proj<<<dim3(8, 64, 3), b256, 0, stream>>>(Qh, Kh, Vh, WQt, WKt, WVt,
                                                     bQ, bK, bV, qx4, kx4, vT);
    // 4) conv A-operand: transpose + zero-pad (over dead Qh/Kh/Vh)
    k_transpose_pad<<<dim3(32, 33, 8), bT, 0, stream>>>(qx4, kx4, XtQ, XtK);
    // 5) conv weight transposes (CTk over dead Vh/WQt -- must be after proj)
    k_ctrans<<<dim3(128, 32, 2), bT, 0, stream>>>(convq, convk, CTq, CTk);
    // 6) fused conv GEMM + residual (z-per-XCD swizzle, coalesced epilogue)
    k_gemm_conv<<<dim3(8, 8, 8), b256, 0, stream>>>(XtQ, XtK, CTq, CTk,
                                                    qx4, kx4, w);
    // 7) flash attention -> ctx (LDS-staged K/V; XCD-friendly grid x=bh)
    k_attn<<<dim3(64, 8), b256, 0, stream>>>(qx4, kx4, vT, ctxb);
    // 8) final projection -> f32 output (chunked swizzle)
    k_gemm_final<<<dim3(8, 32), b256, 0, stream>>>(ctxb, WFt, bfc, (float*)d_out);
}

// Round 18
// 173.915 us; speedup vs baseline: 1.1113x; 1.0086x over previous
//
#include <hip/hip_runtime.h>
#include <hip/hip_bf16.h>

typedef _Float16 f16;
typedef _Float16 f16x2 __attribute__((ext_vector_type(2)));
typedef _Float16 f16x4 __attribute__((ext_vector_type(4)));
typedef _Float16 f16x8 __attribute__((ext_vector_type(8)));
typedef float f32x4 __attribute__((ext_vector_type(4)));

// cvt_pkrtz returns __fp16 ext_vector(2); re-cast to our f16x2 (same bits).
__device__ __forceinline__ f16x2 pkrtz(float a, float b) {
    auto r = __builtin_amdgcn_cvt_pkrtz(a, b);
    f16x2 o; o[0] = (f16)r[0]; o[1] = (f16)r[1];
    return o;
}

#define XT_ROWS 1027
#define XT_BSTRIDE (XT_ROWS * 1024)   // elems per batch

// ---------------------------------------------------------------------------
// global -> LDS direct (16B per lane, wave-uniform LDS base + lane*16)
// ---------------------------------------------------------------------------
__device__ __forceinline__ void gload16(const f16* g, f16* l) {
    __builtin_amdgcn_global_load_lds(
        (const __attribute__((address_space(1))) void*)g,
        (__attribute__((address_space(3))) void*)l, 16, 0, 0);
}

// ---------------------------------------------------------------------------
// Stage a 128x64 f16 tile (16KB).  XOR-swizzle on SOURCE col; same XOR on
// the read side (involution) -> conflict-free ds_read_b128.
// ---------------------------------------------------------------------------
__device__ __forceinline__ void stage_tile(const f16* src, int ld, f16* lds)
{
    const int tid = threadIdx.x;
    const int w512 = (tid >> 6) << 9;          // wave base (f16 elems)
    #pragma unroll
    for (int q = 0; q < 4; ++q) {
        const int s = q * 256 + tid;           // 16B slot id, 0..1023
        const int row = s >> 3;
        const int col = ((s & 7) ^ (row & 7)) << 3;
        gload16(src + row * ld + col, lds + (q << 11) + w512);
    }
}

// ---------------------------------------------------------------------------
// Stage a 64x64 f16 tile (8KB) the same way (512 slots, 2 per thread).
// ---------------------------------------------------------------------------
__device__ __forceinline__ void stage64(const f16* src, int ld, f16* lds)
{
    const int tid = threadIdx.x;
    const int w512 = (tid >> 6) << 9;
    #pragma unroll
    for (int q = 0; q < 2; ++q) {
        const int s = q * 256 + tid;           // 16B slot id, 0..511
        const int row = s >> 3;
        const int col = ((s & 7) ^ (row & 7)) << 3;
        gload16(src + row * ld + col, lds + (q << 11) + w512);
    }
}

// ---------------------------------------------------------------------------
// GEMM core 128x128 (proven 2-barrier structure).
// CONV=1: A row base = m0 + (k0>>10) into zero-padded Xt, col = k0&1023.
// ---------------------------------------------------------------------------
template <int CONV>
__device__ __forceinline__ void gemm_core64(
    const f16* __restrict__ A, int lda, int m0,
    const f16* __restrict__ Bt, int ldb, int K,
    f16* Alds, f16* Blds, f32x4 acc[4][4])
{
    const int tid = threadIdx.x;
    const int lid = tid & 63;
    const int wv  = tid >> 6;
    const int wm  = (wv >> 1) * 64;
    const int wn  = (wv & 1) * 64;
    const int g   = lid >> 4;
    const int r15 = lid & 15;

    stage_tile(A + m0 * lda, lda, Alds);
    stage_tile(Bt, ldb, Blds);
    asm volatile("s_waitcnt vmcnt(0)" ::: "memory");
    __builtin_amdgcn_s_barrier();

    for (int k0 = 0; k0 < K; k0 += 64) {
        f16x8 af[2][4], bf[2][4];
        #pragma unroll
        for (int kc = 0; kc < 2; ++kc) {
            #pragma unroll
            for (int mi = 0; mi < 4; ++mi) {
                const int row = wm + mi * 16 + r15;
                af[kc][mi] = *(const f16x8*)(Alds + row * 64 +
                                             (((kc * 4 + g) ^ (row & 7)) << 3));
            }
            #pragma unroll
            for (int nj = 0; nj < 4; ++nj) {
                const int row = wn + nj * 16 + r15;
                bf[kc][nj] = *(const f16x8*)(Blds + row * 64 +
                                             (((kc * 4 + g) ^ (row & 7)) << 3));
            }
        }
        asm volatile("s_waitcnt lgkmcnt(0)" ::: "memory");
        __builtin_amdgcn_sched_barrier(0);
        __builtin_amdgcn_s_barrier();
        const int k1 = k0 + 64;
        if (k1 < K) {
            const f16* Asrc;
            if (CONV) Asrc = A + (m0 + (k1 >> 10)) * lda + (k1 & 1023);
            else      Asrc = A + m0 * lda + k1;
            stage_tile(Asrc, lda, Alds);
            stage_tile(Bt + k1, ldb, Blds);
        }
        __builtin_amdgcn_sched_barrier(0);
        #pragma unroll
        for (int kc = 0; kc < 2; ++kc)
            #pragma unroll
            for (int mi = 0; mi < 4; ++mi)
                #pragma unroll
                for (int nj = 0; nj < 4; ++nj)
                    acc[mi][nj] = __builtin_amdgcn_mfma_f32_16x16x32_f16(
                        af[kc][mi], bf[kc][nj], acc[mi][nj], 0, 0, 0);
        __builtin_amdgcn_sched_barrier(0);
        asm volatile("s_waitcnt vmcnt(0)" ::: "memory");
        __builtin_amdgcn_s_barrier();
    }
}

// ---------------------------------------------------------------------------
// GEMM core 64x128 (small tile, 24KB LDS -> 2x blocks/CU for TLP hiding).
// Waves 2x2: wave tile 32x64.  acc[2][4].
// CONV=1: A row base = m0 + (k0>>10) into zero-padded Xt, col = k0&1023.
// ---------------------------------------------------------------------------
template <int CONV>
__device__ __forceinline__ void gemm_core_s(
    const f16* __restrict__ A, int lda, int m0,
    const f16* __restrict__ Bt, int ldb, int K,
    f16* Alds, f16* Blds, f32x4 acc[2][4])
{
    const int tid = threadIdx.x;
    const int lid = tid & 63;
    const int wv  = tid >> 6;
    const int wm  = (wv >> 1) * 32;
    const int wn  = (wv & 1) * 64;
    const int g   = lid >> 4;
    const int r15 = lid & 15;

    stage64(A + m0 * lda, lda, Alds);
    stage_tile(Bt, ldb, Blds);
    asm volatile("s_waitcnt vmcnt(0)" ::: "memory");
    __builtin_amdgcn_s_barrier();

    for (int k0 = 0; k0 < K; k0 += 64) {
        f16x8 af[2][2], bf[2][4];
        #pragma unroll
        for (int kc = 0; kc < 2; ++kc) {
            #pragma unroll
            for (int mi = 0; mi < 2; ++mi) {
                const int row = wm + mi * 16 + r15;
                af[kc][mi] = *(const f16x8*)(Alds + row * 64 +
                                             (((kc * 4 + g) ^ (row & 7)) << 3));
            }
            #pragma unroll
            for (int nj = 0; nj < 4; ++nj) {
                const int row = wn + nj * 16 + r15;
                bf[kc][nj] = *(const f16x8*)(Blds + row * 64 +
                                             (((kc * 4 + g) ^ (row & 7)) << 3));
            }
        }
        asm volatile("s_waitcnt lgkmcnt(0)" ::: "memory");
        __builtin_amdgcn_sched_barrier(0);
        __builtin_amdgcn_s_barrier();
        const int k1 = k0 + 64;
        if (k1 < K) {
            const f16* Asrc;
            if (CONV) Asrc = A + (m0 + (k1 >> 10)) * lda + (k1 & 1023);
            else      Asrc = A + m0 * lda + k1;
            stage64(Asrc, lda, Alds);
            stage_tile(Bt + k1, ldb, Blds);
        }
        __builtin_amdgcn_sched_barrier(0);
        #pragma unroll
        for (int kc = 0; kc < 2; ++kc)
            #pragma unroll
            for (int mi = 0; mi < 2; ++mi)
                #pragma unroll
                for (int nj = 0; nj < 4; ++nj)
                    acc[mi][nj] = __builtin_amdgcn_mfma_f32_16x16x32_f16(
                        af[kc][mi], bf[kc][nj], acc[mi][nj], 0, 0, 0);
        __builtin_amdgcn_sched_barrier(0);
        asm volatile("s_waitcnt vmcnt(0)" ::: "memory");
        __builtin_amdgcn_s_barrier();
    }
}

// ---------------------------------------------------------------------------
// Fused fp32 -> fp16 convert for Q,K,V (grid 3*4096 blocks).
// ---------------------------------------------------------------------------
__global__ __launch_bounds__(256) void k_cvt_all(
    const float* __restrict__ Q, const float* __restrict__ K,
    const float* __restrict__ V, f16* __restrict__ Qh,
    f16* __restrict__ Kh, f16* __restrict__ Vh)
{
    const int bid = blockIdx.x;
    const int which = bid >> 12;
    const int i = (bid & 4095) * 256 + threadIdx.x;
    const float* in = which == 0 ? Q : which == 1 ? K : V;
    f16* out = which == 0 ? Qh : which == 1 ? Kh : Vh;
    float4 v = ((const float4*)in)[i];
    f16x4 o;
    o[0] = (f16)v.x; o[1] = (f16)v.y; o[2] = (f16)v.z; o[3] = (f16)v.w;
    ((f16x4*)out)[i] = o;
}

// ---------------------------------------------------------------------------
// Fused transpose+convert for the 4 1024x1024 weights.  grid (32,32,4).
// ---------------------------------------------------------------------------
__global__ __launch_bounds__(256) void k_wtrans(
    const float* __restrict__ WQ, const float* __restrict__ WK,
    const float* __restrict__ WV, const float* __restrict__ Wfc,
    f16* __restrict__ WQt, f16* __restrict__ WKt,
    f16* __restrict__ WVt, f16* __restrict__ WFt)
{
    const int z = blockIdx.z;
    const float* in = z == 0 ? WQ : z == 1 ? WK : z == 2 ? WV : Wfc;
    f16* out = z == 0 ? WQt : z == 1 ? WKt : z == 2 ? WVt : WFt;
    __shared__ float tile[32][33];
    int c0 = blockIdx.x * 32, r0 = blockIdx.y * 32;
    int tx = threadIdx.x, ty = threadIdx.y;
    #pragma unroll
    for (int i = ty; i < 32; i += 8)
        tile[i][tx] = in[(size_t)(r0 + i) * 1024 + c0 + tx];
    __syncthreads();
    #pragma unroll
    for (int i = ty; i < 32; i += 8)
        out[(size_t)(c0 + i) * 1024 + r0 + tx] = (f16)tile[tx][i];
}

// ---------------------------------------------------------------------------
// Fused transpose+convert for conv weights (1024 x 4096).  grid (128,32,2).
// NOTE: must launch AFTER projections — CTk overlays dead Vh/WQt.
// ---------------------------------------------------------------------------
__global__ __launch_bounds__(256) void k_ctrans(
    const float* __restrict__ convq, const float* __restrict__ convk,
    f16* __restrict__ CTq, f16* __restrict__ CTk)
{
    const float* in = blockIdx.z ? convk : convq;
    f16* out = blockIdx.z ? CTk : CTq;
    __shared__ float tile[32][33];
    int c0 = blockIdx.x * 32, r0 = blockIdx.y * 32;
    int tx = threadIdx.x, ty = threadIdx.y;
    #pragma unroll
    for (int i = ty; i < 32; i += 8)
        tile[i][tx] = in[(size_t)(r0 + i) * 4096 + c0 + tx];
    __syncthreads();
    #pragma unroll
    for (int i = ty; i < 32; i += 8)
        out[(size_t)(c0 + i) * 1024 + r0 + tx] = (f16)tile[tx][i];
}

// ---------------------------------------------------------------------------
// Transpose + zero-pad for the conv A-operand.  grid (32,33,8).
// ---------------------------------------------------------------------------
__global__ __launch_bounds__(256) void k_transpose_pad(
    const f16* __restrict__ qx4, const f16* __restrict__ kx4,
    f16* __restrict__ XtQ, f16* __restrict__ XtK)
{
    int z = blockIdx.z, b = z & 3, ten = z >> 2;
    const f16* in = (ten ? kx4 : qx4) + (size_t)b * 1048576;
    f16* out = (ten ? XtK : XtQ) + (size_t)b * XT_BSTRIDE;
    __shared__ f16 tile[32][33];
    int c0 = blockIdx.x * 32;
    int tp0 = blockIdx.y * 32;
    int tx = threadIdx.x, ty = threadIdx.y;
    #pragma unroll
    for (int i = ty; i < 32; i += 8) {
        int t = tp0 + tx - 2;
        tile[i][tx] = (t >= 0 && t < 1024) ? in[(c0 + i) * 1024 + t] : (f16)0.f;
    }
    __syncthreads();
    #pragma unroll
    for (int i = ty; i < 32; i += 8) {
        int tp = tp0 + i;
        if (tp < XT_ROWS) out[tp * 1024 + c0 + tx] = tile[tx][i];
    }
}

// ---------------------------------------------------------------------------
// Projection GEMMs, 64x128 tiles (1536 blocks = 6/CU).  XCD-chunked swizzle
// with xw FAST within each XCD chunk: B tiles (2MB/z) stay L2-resident,
// each 128KB A panel hot for its 8 consecutive blocks -> A fetched ~once.
// z=0: q -> qx4 ; z=1: k -> kx4 ; z=2: v -> vT.  Coalesced epilogue.
// ---------------------------------------------------------------------------
__global__ __launch_bounds__(256) void k_gemm_proj(
    const f16* __restrict__ Qh, const f16* __restrict__ Kh, const f16* __restrict__ Vh,
    const f16* __restrict__ WQt, const f16* __restrict__ WKt, const f16* __restrict__ WVt,
    const float* __restrict__ bQ, const float* __restrict__ bK, const float* __restrict__ bV,
    f16* __restrict__ qx4, f16* __restrict__ kx4, f16* __restrict__ vT)
{
    __shared__ __align__(16) f16 smem[12288];   // A 8KB @0, B 16KB @4096
    const int nid = blockIdx.x + blockIdx.y * 8 + blockIdx.z * 512;
    const int wgid = (nid & 7) * 192 + (nid >> 3);     // bijective, 1536=8*192
    const int z = wgid >> 9, rem = wgid & 511;
    const int xw = rem & 7, yw = rem >> 3;             // xw fast -> B resident
    const f16* A  = z == 0 ? Qh : z == 1 ? Kh : Vh;
    const f16* Bt = z == 0 ? WQt : z == 1 ? WKt : WVt;
    const float* bias = z == 0 ? bQ : z == 1 ? bK : bV;
    f16* dst = z == 0 ? qx4 : z == 1 ? kx4 : vT;
    const int m0 = yw * 64, n0 = xw * 128;
    f32x4 acc[2][4] = {};
    gemm_core_s<0>(A, 1024, m0, Bt + n0 * 1024, 1024, 1024,
                   smem, smem + 4096, acc);

    const int tid = threadIdx.x, lid = tid & 63, wv = tid >> 6;
    const int wm = (wv >> 1) * 32, g = lid >> 4, r15 = lid & 15;
    f16* T = smem;                        // [64][72] = 9216B
    #pragma unroll
    for (int p = 0; p < 2; ++p) {
        __syncthreads();
        if ((wv & 1) == p) {
            #pragma unroll
            for (int nj = 0; nj < 4; ++nj) {
                const int col = n0 + p * 64 + nj * 16 + r15;
                const float bv = bias[col];
                #pragma unroll
                for (int mi = 0; mi < 2; ++mi)
                    #pragma unroll
                    for (int j = 0; j < 4; ++j)
                        T[(wm + mi * 16 + g * 4 + j) * 72 + nj * 16 + r15] =
                            (f16)(acc[mi][nj][j] + bv);
            }
        }
        __syncthreads();
        const int h = (n0 + p * 64) >> 6;
        if (z != 2) {
            #pragma unroll
            for (int q = 0; q < 2; ++q) {
                const int cid = q * 256 + tid;        // 0..511
                const int row = cid >> 3, c = (cid & 7) * 8;
                f16x8 v = *(const f16x8*)(T + row * 72 + c);
                const int grow = m0 + row;
                const int b = grow >> 10, l = grow & 1023;
                *(f16x8*)(dst + b * 1048576 + h * 65536 + l * 64 + c) = v;
            }
        } else {
            const int b = m0 >> 10, l0 = m0 & 1023;
            #pragma unroll
            for (int q = 0; q < 2; ++q) {
                const int cid = q * 256 + tid;        // 0..511
                const int d = cid >> 3, lc = (cid & 7) * 8;
                f16x8 v;
                #pragma unroll
                for (int e = 0; e < 8; ++e) v[e] = T[(lc + e) * 72 + d];
                *(f16x8*)(dst + b * 1048576 + h * 65536 + d * 1024 + l0 + lc) = v;
            }
        }
    }
}

// ---------------------------------------------------------------------------
// Fused conv GEMM + residual, 64x128 tiles (1024 blocks = 4/CU).
// z = nid&7 per-XCD (A 2MB Xt L2-resident); inner yw fast (CT tile hot).
// Epilogue: LDS transpose + coalesced f16x8 residual read/add/write.
// ---------------------------------------------------------------------------
__global__ __launch_bounds__(256) void k_gemm_conv(
    const f16* __restrict__ XtQ, const f16* __restrict__ XtK,
    const f16* __restrict__ CTq, const f16* __restrict__ CTk,
    f16* __restrict__ qx4, f16* __restrict__ kx4,
    const float* __restrict__ wvec)
{
    __shared__ __align__(16) f16 smem[12288];   // A 8KB @0, B 16KB @4096
    const int nid = blockIdx.x + blockIdx.y * 8 + blockIdx.z * 128;
    const int z = nid & 7;                 // XCD-resident (tensor,batch)
    const int inner = nid >> 3;            // 0..127
    const int yw = inner & 15;             // m-tile (fast; A L2-resident)
    const int xw = inner >> 4;             // n-tile (slow; CT tile hot)
    const int b = z & 3, ten = z >> 2;
    const f16* Xt = (ten ? XtK : XtQ) + (size_t)b * XT_BSTRIDE;
    const f16* CT = ten ? CTk : CTq;
    f16* dst = (ten ? kx4 : qx4) + (size_t)b * 1048576;

    const int flen = (2.f * wvec[0] >= 4.f * wvec[1]) ? 2 : 4;
    const int K = flen << 10;

    const int m0 = yw * 64, n0 = xw * 128;
    f32x4 acc[2][4] = {};
    gemm_core_s<1>(Xt, 1024, m0, CT + n0 * 4096, 4096, K,
                   smem, smem + 4096, acc);

    const int tid = threadIdx.x, lid = tid & 63, wv = tid >> 6;
    const int wm = (wv >> 1) * 32, g = lid >> 4, r15 = lid & 15;
    f16* T = smem;                        // [64][72]
    #pragma unroll
    for (int p = 0; p < 2; ++p) {
        __syncthreads();
        if ((wv & 1) == p) {
            #pragma unroll
            for (int nj = 0; nj < 4; ++nj)
                #pragma unroll
                for (int mi = 0; mi < 2; ++mi)
                    #pragma unroll
                    for (int j = 0; j < 4; ++j)
                        T[(wm + mi * 16 + g * 4 + j) * 72 + nj * 16 + r15] =
                            (f16)acc[mi][nj][j];
        }
        __syncthreads();
        #pragma unroll
        for (int q = 0; q < 2; ++q) {
            const int cid = q * 256 + tid;            // 0..511
            const int row = cid >> 3, c = (cid & 7) * 8;
            f16x8 v = *(const f16x8*)(T + row * 72 + c);
            f16* pdst = dst + (size_t)(m0 + row) * 1024 + n0 + p * 64 + c;
            f16x8 r = *(const f16x8*)pdst;
            f16x8 o2;
            #pragma unroll
            for (int e = 0; e < 8; ++e)
                o2[e] = (f16)((float)v[e] + (float)r[e]);
            *(f16x8*)pdst = o2;
        }
    }
}

// ---------------------------------------------------------------------------
// Flash attention with LDS-staged K/V tiles + double-buffered raw-barrier
// pipeline.  grid (64 bh, 8 qt).  Swapped QK^T; constant-shift exp;
// deferred row-sum; sigma' k-slot bijection on both PV operands.
// ---------------------------------------------------------------------------
__device__ __forceinline__ void attn_tile(
    const f16* KL, const f16* VL,
    const f16* Kn, const f16* Vn, f16* KLn, f16* VLn, bool doStage,
    const f16x8 qf[2][2], f32x4 o[2][4], f32x4 lsum[2], int g, int r15)
{
    f16x8 kf[4][2];
    #pragma unroll
    for (int nj = 0; nj < 4; ++nj)
        #pragma unroll
        for (int kc = 0; kc < 2; ++kc) {
            const int row = nj * 16 + r15;
            kf[nj][kc] = *(const f16x8*)(KL + row * 64 +
                                         (((kc * 4 + g) ^ (row & 7)) << 3));
        }
    f16x4 vlo[4][2], vhi[4][2];
    #pragma unroll
    for (int db = 0; db < 4; ++db)
        #pragma unroll
        for (int ch = 0; ch < 2; ++ch) {
            const int row = db * 16 + r15;
            const int c1 = ch * 4 + (g >> 1);
            const int c2 = c1 + 2;
            const int sub = (g & 1) * 4;
            vlo[db][ch] = *(const f16x4*)(VL + row * 64 +
                                          ((c1 ^ (row & 7)) << 3) + sub);
            vhi[db][ch] = *(const f16x4*)(VL + row * 64 +
                                          ((c2 ^ (row & 7)) << 3) + sub);
        }
    asm volatile("s_waitcnt lgkmcnt(0)" ::: "memory");
    __builtin_amdgcn_sched_barrier(0);
    __builtin_amdgcn_s_barrier();
    if (doStage) {
        stage64(Kn, 64, KLn);
        stage64(Vn, 1024, VLn);
    }
    __builtin_amdgcn_sched_barrier(0);
    f32x4 sacc[2][4] = {};
    #pragma unroll
    for (int nj = 0; nj < 4; ++nj)
        #pragma unroll
        for (int kc = 0; kc < 2; ++kc) {
            sacc[0][nj] = __builtin_amdgcn_mfma_f32_16x16x32_f16(
                kf[nj][kc], qf[0][kc], sacc[0][nj], 0, 0, 0);
            sacc[1][nj] = __builtin_amdgcn_mfma_f32_16x16x32_f16(
                kf[nj][kc], qf[1][kc], sacc[1][nj], 0, 0, 0);
        }
    #pragma unroll
    for (int qh = 0; qh < 2; ++qh) {
        f32x4 pe[4];
        #pragma unroll
        for (int nj = 0; nj < 4; ++nj) {
            #pragma unroll
            for (int j = 0; j < 4; ++j)
                pe[nj][j] = __expf(sacc[qh][nj][j] - 2.0f);
            lsum[qh] += pe[nj];
        }
        f16x8 pb[2];
        #pragma unroll
        for (int ch = 0; ch < 2; ++ch) {
            union { f16x2 h2[4]; f16x8 v8; } u;
            u.h2[0] = pkrtz(pe[2 * ch][0], pe[2 * ch][1]);
            u.h2[1] = pkrtz(pe[2 * ch][2], pe[2 * ch][3]);
            u.h2[2] = pkrtz(pe[2 * ch + 1][0], pe[2 * ch + 1][1]);
            u.h2[3] = pkrtz(pe[2 * ch + 1][2], pe[2 * ch + 1][3]);
            pb[ch] = u.v8;
        }
        #pragma unroll
        for (int db = 0; db < 4; ++db)
            #pragma unroll
            for (int ch = 0; ch < 2; ++ch) {
                union { f16x4 h4[2]; f16x8 v8; } w;
                w.h4[0] = vlo[db][ch];
                w.h4[1] = vhi[db][ch];
                o[qh][db] = __builtin_amdgcn_mfma_f32_16x16x32_f16(
                    w.v8, pb[ch], o[qh][db], 0, 0, 0);
            }
    }
    __builtin_amdgcn_sched_barrier(0);
    asm volatile("s_waitcnt vmcnt(0)" ::: "memory");
    __builtin_amdgcn_s_barrier();
}

__global__ __launch_bounds__(256) void k_attn(
    const f16* __restrict__ qn, const f16* __restrict__ kn,
    const f16* __restrict__ vT, f16* __restrict__ ctx)
{
    __shared__ __align__(16) f16 lds[4][4096];   // K0 V0 K1 V1
    const int bh = blockIdx.x, b = bh >> 4, h = bh & 15;
    const f16* Qp = qn + (size_t)b * 1048576 + h * 65536;
    const f16* Kp = kn + (size_t)b * 1048576 + h * 65536;
    const f16* Vp = vT + (size_t)b * 1048576 + h * 65536;
    const int tid = threadIdx.x, lid = tid & 63, wv = tid >> 6;
    const int g = lid >> 4, r15 = lid & 15;
    const int q0 = blockIdx.y * 128 + wv * 32;

    f16x8 qf[2][2];
    #pragma unroll
    for (int qh = 0; qh < 2; ++qh)
        #pragma unroll
        for (int kc = 0; kc < 2; ++kc) {
            f16x8 t = *(const f16x8*)(Qp + (q0 + qh * 16 + r15) * 64 + kc * 32 + g * 8);
            #pragma unroll
            for (int e = 0; e < 8; ++e) t[e] = t[e] * (f16)0.125f;
            qf[qh][kc] = t;
        }

    f32x4 o[2][4] = {};
    f32x4 lsum[2] = {};

    stage64(Kp, 64, lds[0]);
    stage64(Vp, 1024, lds[1]);
    asm volatile("s_waitcnt vmcnt(0)" ::: "memory");
    __builtin_amdgcn_s_barrier();

    for (int tt = 0; tt < 8; ++tt) {
        const int t1 = 2 * tt + 1;
        attn_tile(lds[0], lds[1], Kp + t1 * 4096, Vp + t1 * 64,
                  lds[2], lds[3], true, qf, o, lsum, g, r15);
        attn_tile(lds[2], lds[3], Kp + (t1 + 1) * 4096, Vp + (t1 + 1) * 64,
                  lds[0], lds[1], tt < 7, qf, o, lsum, g, r15);
    }

    float inv[2];
    #pragma unroll
    for (int qh = 0; qh < 2; ++qh) {
        float lr = lsum[qh][0] + lsum[qh][1] + lsum[qh][2] + lsum[qh][3];
        lr += __shfl_xor(lr, 16);
        lr += __shfl_xor(lr, 32);
        inv[qh] = 1.0f / lr;
    }
    f16* Olds = &lds[0][0] + wv * (32 * 72);
    #pragma unroll
    for (int qh = 0; qh < 2; ++qh)
        #pragma unroll
        for (int db = 0; db < 4; ++db) {
            const int row = qh * 16 + r15, col = db * 16 + g * 4;
            *(f16x2*)(Olds + row * 72 + col) =
                pkrtz(o[qh][db][0] * inv[qh], o[qh][db][1] * inv[qh]);
            *(f16x2*)(Olds + row * 72 + col + 2) =
                pkrtz(o[qh][db][2] * inv[qh], o[qh][db][3] * inv[qh]);
        }
    asm volatile("s_waitcnt lgkmcnt(0)" ::: "memory");
    __builtin_amdgcn_sched_barrier(0);
    #pragma unroll
    for (int p = 0; p < 4; ++p) {
        const int row = p * 8 + (lid >> 3);
        const int c8 = (lid & 7) * 8;
        f16x8 v = *(const f16x8*)(Olds + row * 72 + c8);
        *(f16x8*)(ctx + (size_t)b * 1048576 + (q0 + row) * 1024 + h * 64 + c8) = v;
    }
}

// ---------------------------------------------------------------------------
// Final GEMM: out = ctx @ Wfc + bfc, output FLOAT32.  Chunked XCD swizzle
// (xw already fast -> WFt L2-resident).
// ---------------------------------------------------------------------------
__global__ __launch_bounds__(256) void k_gemm_final(
    const f16* __restrict__ ctx, const f16* __restrict__ WFt,
    const float* __restrict__ bfc, float* __restrict__ out)
{
    __shared__ __align__(16) f16 smem[16384];
    const int nid = blockIdx.x + blockIdx.y * 8;
    const int wgid = (nid & 7) * 32 + (nid >> 3);      // bijective, 256=8*32
    const int xw = wgid & 7, yw = wgid >> 3;
    const int m0 = yw * 128, n0 = xw * 128;
    f32x4 acc[4][4] = {};
    gemm_core64<0>(ctx, 1024, m0, WFt + n0 * 1024, 1024, 1024,
                   smem, smem + 8192, acc);

    const int tid = threadIdx.x, lid = tid & 63, wv = tid >> 6;
    const int wm = (wv >> 1) * 64, wn = (wv & 1) * 64, g = lid >> 4, r15 = lid & 15;
    #pragma unroll
    for (int nj = 0; nj < 4; ++nj) {
        const int col = n0 + wn + nj * 16 + r15;
        const float bv = bfc[col];
        #pragma unroll
        for (int mi = 0; mi < 4; ++mi)
            #pragma unroll
            for (int j = 0; j < 4; ++j) {
                const int row = m0 + wm + mi * 16 + g * 4 + j;
                out[(size_t)row * 1024 + col] = acc[mi][nj][j] + bv;
            }
    }
}

// ---------------------------------------------------------------------------
// Workspace (64 MiB), round-15 layout:
//   qx4 @0  kx4 @8M  vT @16M  WFt @24M (live: proj..final)
//   Qh @26M  Kh @34M  Vh @42M  WQt @50M  WKt @52M  WVt @54M  CTq @56M
//   After proj: XtQ @26M  XtK @34.03M  CTk @42.05M (over dead Vh/WQt)
//   After conv: ctxb @26M over dead XtQ (attn -> final)
//   ORDER: k_ctrans AFTER k_gemm_proj (CTk overlays Vh/WQt).
// ---------------------------------------------------------------------------
extern "C" void kernel_launch(void* const* d_in, const int* in_sizes, int n_in,
                              void* d_out, int out_size, void* d_ws, size_t ws_size,
                              hipStream_t stream)
{
    (void)in_sizes; (void)n_in; (void)out_size; (void)ws_size;
    const float* Q     = (const float*)d_in[0];
    const float* K     = (const float*)d_in[1];
    const float* V     = (const float*)d_in[2];
    // d_in[3] = attn_mask (unused by reference)
    const float* WQ    = (const float*)d_in[4];
    const float* bQ    = (const float*)d_in[5];
    const float* WK    = (const float*)d_in[6];
    const float* bK    = (const float*)d_in[7];
    const float* WV    = (const float*)d_in[8];
    const float* bV    = (const float*)d_in[9];
    const float* Wfc   = (const float*)d_in[10];
    const float* bfc   = (const float*)d_in[11];
    const float* convq = (const float*)d_in[12];
    const float* convk = (const float*)d_in[13];
    const float* w     = (const float*)d_in[14];

    char* ws = (char*)d_ws;
    f16* qx4   = (f16*)(ws + 0);
    f16* kx4   = (f16*)(ws + 8388608);
    f16* vT    = (f16*)(ws + 16777216);
    f16* WFt   = (f16*)(ws + 25165824);
    f16* Qh    = (f16*)(ws + 27262976);
    f16* Kh    = (f16*)(ws + 35651584);
    f16* Vh    = (f16*)(ws + 44040192);
    f16* WQt   = (f16*)(ws + 52428800);
    f16* WKt   = (f16*)(ws + 54525952);
    f16* WVt   = (f16*)(ws + 56623104);
    f16* CTq   = (f16*)(ws + 58720256);
    f16* XtQ   = (f16*)(ws + 27262976);  // over dead Qh (+Kh head)
    f16* XtK   = (f16*)(ws + 35676160);  // over dead Kh (+Vh head)
    f16* CTk   = (f16*)(ws + 44089344);  // over dead Vh (+WQt head) - AFTER proj!
    f16* ctxb  = (f16*)(ws + 27262976);  // over dead XtQ (attn->final)

    dim3 b256(256), bT(32, 8);

    // 1) fp32 -> fp16 inputs
    k_cvt_all<<<12288, b256, 0, stream>>>(Q, K, V, Qh, Kh, Vh);
    // 2) weight transposes for projections
    k_wtrans<<<dim3(32, 32, 4), bT, 0, stream>>>(WQ, WK, WV, Wfc,
                                                 WQt, WKt, WVt, WFt);
    // 3) projections (64x128 tiles; xw-fast swizzle -> minimal fetch)
    k_gemm_proj<<<dim3(8, 64, 3), b256, 0, stream>>>(Qh, Kh, Vh, WQt, WKt, WVt,
                                                     bQ, bK, bV, qx4, kx4, vT);
    // 4) conv A-operand: transpose + zero-pad (over dead Qh/Kh/Vh)
    k_transpose_pad<<<dim3(32, 33, 8), bT, 0, stream>>>(qx4, kx4, XtQ, XtK);
    // 5) conv weight transposes (CTk over dead Vh/WQt -- must be after proj)
    k_ctrans<<<dim3(128, 32, 2), bT, 0, stream>>>(convq, convk, CTq, CTk);
    // 6) fused conv GEMM + residual (64x128 tiles, 1024 blocks = 4/CU)
    k_gemm_conv<<<dim3(8, 16, 8), b256, 0, stream>>>(XtQ, XtK, CTq, CTk,
                                                     qx4, kx4, w);
    // 7) flash attention -> ctx (LDS-staged K/V; XCD-friendly grid x=bh)
    k_attn<<<dim3(64, 8), b256, 0, stream>>>(qx4, kx4, vT, ctxb);
    // 8) final projection -> f32 output (chunked swizzle)
    k_gemm_final<<<dim3(8, 32), b256, 0, stream>>>(ctxb, WFt, bfc, (float*)d_out);
}

// Round 19
// 163.195 us; speedup vs baseline: 1.1843x; 1.0657x over previous
//
#include <hip/hip_runtime.h>
#include <hip/hip_bf16.h>

typedef _Float16 f16;
typedef _Float16 f16x2 __attribute__((ext_vector_type(2)));
typedef _Float16 f16x4 __attribute__((ext_vector_type(4)));
typedef _Float16 f16x8 __attribute__((ext_vector_type(8)));
typedef float f32x4 __attribute__((ext_vector_type(4)));

// cvt_pkrtz returns __fp16 ext_vector(2); re-cast to our f16x2 (same bits).
__device__ __forceinline__ f16x2 pkrtz(float a, float b) {
    auto r = __builtin_amdgcn_cvt_pkrtz(a, b);
    f16x2 o; o[0] = (f16)r[0]; o[1] = (f16)r[1];
    return o;
}

#define XT_ROWS 1027
#define XT_BSTRIDE (XT_ROWS * 1024)   // elems per batch

// ---------------------------------------------------------------------------
// global -> LDS direct (16B per lane, wave-uniform LDS base + lane*16)
// ---------------------------------------------------------------------------
__device__ __forceinline__ void gload16(const f16* g, f16* l) {
    __builtin_amdgcn_global_load_lds(
        (const __attribute__((address_space(1))) void*)g,
        (__attribute__((address_space(3))) void*)l, 16, 0, 0);
}

// ---------------------------------------------------------------------------
// Stage a 128x64 f16 tile (16KB).  XOR-swizzle on SOURCE col; same XOR on
// the read side (involution) -> conflict-free ds_read_b128.
// ---------------------------------------------------------------------------
__device__ __forceinline__ void stage_tile(const f16* src, int ld, f16* lds)
{
    const int tid = threadIdx.x;
    const int w512 = (tid >> 6) << 9;          // wave base (f16 elems)
    #pragma unroll
    for (int q = 0; q < 4; ++q) {
        const int s = q * 256 + tid;           // 16B slot id, 0..1023
        const int row = s >> 3;
        const int col = ((s & 7) ^ (row & 7)) << 3;
        gload16(src + row * ld + col, lds + (q << 11) + w512);
    }
}

// ---------------------------------------------------------------------------
// Stage a 64x64 f16 tile (8KB) the same way (512 slots, 2 per thread).
// ---------------------------------------------------------------------------
__device__ __forceinline__ void stage64(const f16* src, int ld, f16* lds)
{
    const int tid = threadIdx.x;
    const int w512 = (tid >> 6) << 9;
    #pragma unroll
    for (int q = 0; q < 2; ++q) {
        const int s = q * 256 + tid;           // 16B slot id, 0..511
        const int row = s >> 3;
        const int col = ((s & 7) ^ (row & 7)) << 3;
        gload16(src + row * ld + col, lds + (q << 11) + w512);
    }
}

// ---------------------------------------------------------------------------
// GEMM core 128x128 (proven 2-barrier structure).
// CONV=1: A row base = m0 + (k0>>10) into zero-padded Xt, col = k0&1023.
// ---------------------------------------------------------------------------
template <int CONV>
__device__ __forceinline__ void gemm_core64(
    const f16* __restrict__ A, int lda, int m0,
    const f16* __restrict__ Bt, int ldb, int K,
    f16* Alds, f16* Blds, f32x4 acc[4][4])
{
    const int tid = threadIdx.x;
    const int lid = tid & 63;
    const int wv  = tid >> 6;
    const int wm  = (wv >> 1) * 64;
    const int wn  = (wv & 1) * 64;
    const int g   = lid >> 4;
    const int r15 = lid & 15;

    stage_tile(A + m0 * lda, lda, Alds);
    stage_tile(Bt, ldb, Blds);
    asm volatile("s_waitcnt vmcnt(0)" ::: "memory");
    __builtin_amdgcn_s_barrier();

    for (int k0 = 0; k0 < K; k0 += 64) {
        f16x8 af[2][4], bf[2][4];
        #pragma unroll
        for (int kc = 0; kc < 2; ++kc) {
            #pragma unroll
            for (int mi = 0; mi < 4; ++mi) {
                const int row = wm + mi * 16 + r15;
                af[kc][mi] = *(const f16x8*)(Alds + row * 64 +
                                             (((kc * 4 + g) ^ (row & 7)) << 3));
            }
            #pragma unroll
            for (int nj = 0; nj < 4; ++nj) {
                const int row = wn + nj * 16 + r15;
                bf[kc][nj] = *(const f16x8*)(Blds + row * 64 +
                                             (((kc * 4 + g) ^ (row & 7)) << 3));
            }
        }
        asm volatile("s_waitcnt lgkmcnt(0)" ::: "memory");
        __builtin_amdgcn_sched_barrier(0);
        __builtin_amdgcn_s_barrier();
        const int k1 = k0 + 64;
        if (k1 < K) {
            const f16* Asrc;
            if (CONV) Asrc = A + (m0 + (k1 >> 10)) * lda + (k1 & 1023);
            else      Asrc = A + m0 * lda + k1;
            stage_tile(Asrc, lda, Alds);
            stage_tile(Bt + k1, ldb, Blds);
        }
        __builtin_amdgcn_sched_barrier(0);
        #pragma unroll
        for (int kc = 0; kc < 2; ++kc)
            #pragma unroll
            for (int mi = 0; mi < 4; ++mi)
                #pragma unroll
                for (int nj = 0; nj < 4; ++nj)
                    acc[mi][nj] = __builtin_amdgcn_mfma_f32_16x16x32_f16(
                        af[kc][mi], bf[kc][nj], acc[mi][nj], 0, 0, 0);
        __builtin_amdgcn_sched_barrier(0);
        asm volatile("s_waitcnt vmcnt(0)" ::: "memory");
        __builtin_amdgcn_s_barrier();
    }
}

// ---------------------------------------------------------------------------
// GEMM core 64x128 (small tile, 24KB LDS -> 6 blocks/CU for TLP hiding).
// Waves 2x2: wave tile 32x64.  acc[2][4].
// ---------------------------------------------------------------------------
template <int CONV>
__device__ __forceinline__ void gemm_core_s(
    const f16* __restrict__ A, int lda, int m0,
    const f16* __restrict__ Bt, int ldb, int K,
    f16* Alds, f16* Blds, f32x4 acc[2][4])
{
    const int tid = threadIdx.x;
    const int lid = tid & 63;
    const int wv  = tid >> 6;
    const int wm  = (wv >> 1) * 32;
    const int wn  = (wv & 1) * 64;
    const int g   = lid >> 4;
    const int r15 = lid & 15;

    stage64(A + m0 * lda, lda, Alds);
    stage_tile(Bt, ldb, Blds);
    asm volatile("s_waitcnt vmcnt(0)" ::: "memory");
    __builtin_amdgcn_s_barrier();

    for (int k0 = 0; k0 < K; k0 += 64) {
        f16x8 af[2][2], bf[2][4];
        #pragma unroll
        for (int kc = 0; kc < 2; ++kc) {
            #pragma unroll
            for (int mi = 0; mi < 2; ++mi) {
                const int row = wm + mi * 16 + r15;
                af[kc][mi] = *(const f16x8*)(Alds + row * 64 +
                                             (((kc * 4 + g) ^ (row & 7)) << 3));
            }
            #pragma unroll
            for (int nj = 0; nj < 4; ++nj) {
                const int row = wn + nj * 16 + r15;
                bf[kc][nj] = *(const f16x8*)(Blds + row * 64 +
                                             (((kc * 4 + g) ^ (row & 7)) << 3));
            }
        }
        asm volatile("s_waitcnt lgkmcnt(0)" ::: "memory");
        __builtin_amdgcn_sched_barrier(0);
        __builtin_amdgcn_s_barrier();
        const int k1 = k0 + 64;
        if (k1 < K) {
            const f16* Asrc;
            if (CONV) Asrc = A + (m0 + (k1 >> 10)) * lda + (k1 & 1023);
            else      Asrc = A + m0 * lda + k1;
            stage64(Asrc, lda, Alds);
            stage_tile(Bt + k1, ldb, Blds);
        }
        __builtin_amdgcn_sched_barrier(0);
        #pragma unroll
        for (int kc = 0; kc < 2; ++kc)
            #pragma unroll
            for (int mi = 0; mi < 2; ++mi)
                #pragma unroll
                for (int nj = 0; nj < 4; ++nj)
                    acc[mi][nj] = __builtin_amdgcn_mfma_f32_16x16x32_f16(
                        af[kc][mi], bf[kc][nj], acc[mi][nj], 0, 0, 0);
        __builtin_amdgcn_sched_barrier(0);
        asm volatile("s_waitcnt vmcnt(0)" ::: "memory");
        __builtin_amdgcn_s_barrier();
    }
}

// ---------------------------------------------------------------------------
// Merged preproc 1: cvt Q/K/V (blocks 0..12287) + weight transposes
// (blocks 12288..16383; 1024 blocks per weight).
// ---------------------------------------------------------------------------
__global__ __launch_bounds__(256) void k_pre(
    const float* __restrict__ Q, const float* __restrict__ K,
    const float* __restrict__ V,
    const float* __restrict__ WQ, const float* __restrict__ WK,
    const float* __restrict__ WV, const float* __restrict__ Wfc,
    f16* __restrict__ Qh, f16* __restrict__ Kh, f16* __restrict__ Vh,
    f16* __restrict__ WQt, f16* __restrict__ WKt,
    f16* __restrict__ WVt, f16* __restrict__ WFt)
{
    __shared__ float tile[32][33];
    const int bid = blockIdx.x, tid = threadIdx.x;
    if (bid < 12288) {
        const int which = bid >> 12;
        const int i = (bid & 4095) * 256 + tid;
        const float* in = which == 0 ? Q : which == 1 ? K : V;
        f16* out = which == 0 ? Qh : which == 1 ? Kh : Vh;
        float4 v = ((const float4*)in)[i];
        f16x4 o;
        o[0] = (f16)v.x; o[1] = (f16)v.y; o[2] = (f16)v.z; o[3] = (f16)v.w;
        ((f16x4*)out)[i] = o;
    } else {
        const int wb = bid - 12288;
        const int z = wb >> 10;
        const int xy = wb & 1023;
        const int c0 = (xy & 31) * 32, r0 = (xy >> 5) * 32;
        const float* in = z == 0 ? WQ : z == 1 ? WK : z == 2 ? WV : Wfc;
        f16* out = z == 0 ? WQt : z == 1 ? WKt : z == 2 ? WVt : WFt;
        const int tx = tid & 31, ty = tid >> 5;
        #pragma unroll
        for (int i = ty; i < 32; i += 8)
            tile[i][tx] = in[(size_t)(r0 + i) * 1024 + c0 + tx];
        __syncthreads();
        #pragma unroll
        for (int i = ty; i < 32; i += 8)
            out[(size_t)(c0 + i) * 1024 + r0 + tx] = (f16)tile[tx][i];
    }
}

// ---------------------------------------------------------------------------
// Merged preproc 2 (AFTER proj — CTk overlays dead Vh/WQt):
// conv-weight transposes (blocks 0..8191) + Xt transpose-pad (8192..16639).
// ---------------------------------------------------------------------------
__global__ __launch_bounds__(256) void k_mid(
    const float* __restrict__ convq, const float* __restrict__ convk,
    f16* __restrict__ CTq, f16* __restrict__ CTk,
    const f16* __restrict__ qx4, const f16* __restrict__ kx4,
    f16* __restrict__ XtQ, f16* __restrict__ XtK)
{
    __shared__ __align__(16) float tbuf[32][33];
    const int bid = blockIdx.x, tid = threadIdx.x;
    const int tx = tid & 31, ty = tid >> 5;
    if (bid < 8192) {
        const int z = bid >> 12;
        const int xy = bid & 4095;
        const int c0 = (xy & 127) * 32, r0 = (xy >> 7) * 32;
        const float* in = z ? convk : convq;
        f16* out = z ? CTk : CTq;
        #pragma unroll
        for (int i = ty; i < 32; i += 8)
            tbuf[i][tx] = in[(size_t)(r0 + i) * 4096 + c0 + tx];
        __syncthreads();
        #pragma unroll
        for (int i = ty; i < 32; i += 8)
            out[(size_t)(c0 + i) * 1024 + r0 + tx] = (f16)tbuf[tx][i];
    } else {
        const int pb = bid - 8192;
        const int z = pb / 1056, rem = pb % 1056;
        const int b = z & 3, ten = z >> 2;
        const int c0 = (rem & 31) * 32;
        const int tp0 = (rem >> 5) * 32;
        const f16* in = (ten ? kx4 : qx4) + (size_t)b * 1048576;
        f16* out = (ten ? XtK : XtQ) + (size_t)b * XT_BSTRIDE;
        f16* tile = (f16*)tbuf;             // [32][33] f16
        #pragma unroll
        for (int i = ty; i < 32; i += 8) {
            int t = tp0 + tx - 2;
            tile[i * 33 + tx] = (t >= 0 && t < 1024)
                                ? in[(c0 + i) * 1024 + t] : (f16)0.f;
        }
        __syncthreads();
        #pragma unroll
        for (int i = ty; i < 32; i += 8) {
            int tp = tp0 + i;
            if (tp < XT_ROWS) out[tp * 1024 + c0 + tx] = tile[tx * 33 + i];
        }
    }
}

// ---------------------------------------------------------------------------
// Projection GEMMs, 64x128 tiles (1536 blocks = 6/CU).  XCD-chunked swizzle
// with xw FAST: B tiles stay L2-resident; each 128KB A panel hot for its 8
// consecutive blocks.  z=0: q -> qx4 ; z=1: k ; z=2: v -> vT.
// ---------------------------------------------------------------------------
__global__ __launch_bounds__(256) void k_gemm_proj(
    const f16* __restrict__ Qh, const f16* __restrict__ Kh, const f16* __restrict__ Vh,
    const f16* __restrict__ WQt, const f16* __restrict__ WKt, const f16* __restrict__ WVt,
    const float* __restrict__ bQ, const float* __restrict__ bK, const float* __restrict__ bV,
    f16* __restrict__ qx4, f16* __restrict__ kx4, f16* __restrict__ vT)
{
    __shared__ __align__(16) f16 smem[12288];   // A 8KB @0, B 16KB @4096
    const int nid = blockIdx.x + blockIdx.y * 8 + blockIdx.z * 512;
    const int wgid = (nid & 7) * 192 + (nid >> 3);     // bijective, 1536=8*192
    const int z = wgid >> 9, rem = wgid & 511;
    const int xw = rem & 7, yw = rem >> 3;             // xw fast -> B resident
    const f16* A  = z == 0 ? Qh : z == 1 ? Kh : Vh;
    const f16* Bt = z == 0 ? WQt : z == 1 ? WKt : WVt;
    const float* bias = z == 0 ? bQ : z == 1 ? bK : bV;
    f16* dst = z == 0 ? qx4 : z == 1 ? kx4 : vT;
    const int m0 = yw * 64, n0 = xw * 128;
    f32x4 acc[2][4] = {};
    gemm_core_s<0>(A, 1024, m0, Bt + n0 * 1024, 1024, 1024,
                   smem, smem + 4096, acc);

    const int tid = threadIdx.x, lid = tid & 63, wv = tid >> 6;
    const int wm = (wv >> 1) * 32, g = lid >> 4, r15 = lid & 15;
    f16* T = smem;                        // [64][72] = 9216B
    #pragma unroll
    for (int p = 0; p < 2; ++p) {
        __syncthreads();
        if ((wv & 1) == p) {
            #pragma unroll
            for (int nj = 0; nj < 4; ++nj) {
                const int col = n0 + p * 64 + nj * 16 + r15;
                const float bv = bias[col];
                #pragma unroll
                for (int mi = 0; mi < 2; ++mi)
                    #pragma unroll
                    for (int j = 0; j < 4; ++j)
                        T[(wm + mi * 16 + g * 4 + j) * 72 + nj * 16 + r15] =
                            (f16)(acc[mi][nj][j] + bv);
            }
        }
        __syncthreads();
        const int h = (n0 + p * 64) >> 6;
        if (z != 2) {
            #pragma unroll
            for (int q = 0; q < 2; ++q) {
                const int cid = q * 256 + tid;        // 0..511
                const int row = cid >> 3, c = (cid & 7) * 8;
                f16x8 v = *(const f16x8*)(T + row * 72 + c);
                const int grow = m0 + row;
                const int b = grow >> 10, l = grow & 1023;
                *(f16x8*)(dst + b * 1048576 + h * 65536 + l * 64 + c) = v;
            }
        } else {
            const int b = m0 >> 10, l0 = m0 & 1023;
            #pragma unroll
            for (int q = 0; q < 2; ++q) {
                const int cid = q * 256 + tid;        // 0..511
                const int d = cid >> 3, lc = (cid & 7) * 8;
                f16x8 v;
                #pragma unroll
                for (int e = 0; e < 8; ++e) v[e] = T[(lc + e) * 72 + d];
                *(f16x8*)(dst + b * 1048576 + h * 65536 + d * 1024 + l0 + lc) = v;
            }
        }
    }
}

// ---------------------------------------------------------------------------
// Fused conv GEMM + residual, 128x128 tiles (512 blocks, z-per-XCD swizzle;
// yw fast inner so CT tile hot, A Xt 2MB L2-resident).
// Epilogue: LDS transpose + coalesced f16x8 residual read/add/write.
// ---------------------------------------------------------------------------
__global__ __launch_bounds__(256) void k_gemm_conv(
    const f16* __restrict__ XtQ, const f16* __restrict__ XtK,
    const f16* __restrict__ CTq, const f16* __restrict__ CTk,
    f16* __restrict__ qx4, f16* __restrict__ kx4,
    const float* __restrict__ wvec)
{
    __shared__ __align__(16) f16 smem[16384];
    const int nid = blockIdx.x + blockIdx.y * 8 + blockIdx.z * 64;
    const int z = nid & 7;                 // XCD-resident (tensor,batch)
    const int inner = nid >> 3;            // 0..63
    const int yw = inner & 7;              // m-tile (fast; A cycles in L2)
    const int xw = inner >> 3;             // n-tile (slow; CT tile hot)
    const int b = z & 3, ten = z >> 2;
    const f16* Xt = (ten ? XtK : XtQ) + (size_t)b * XT_BSTRIDE;
    const f16* CT = ten ? CTk : CTq;
    f16* dst = (ten ? kx4 : qx4) + (size_t)b * 1048576;

    const int flen = (2.f * wvec[0] >= 4.f * wvec[1]) ? 2 : 4;
    const int K = flen << 10;

    const int m0 = yw * 128, n0 = xw * 128;
    f32x4 acc[4][4] = {};
    gemm_core64<1>(Xt, 1024, m0, CT + n0 * 4096, 4096, K,
                   smem, smem + 8192, acc);

    const int tid = threadIdx.x, lid = tid & 63, wv = tid >> 6;
    const int wm = (wv >> 1) * 64, g = lid >> 4, r15 = lid & 15;
    f16* T = smem;
    #pragma unroll
    for (int p = 0; p < 2; ++p) {
        __syncthreads();
        if ((wv & 1) == p) {
            #pragma unroll
            for (int nj = 0; nj < 4; ++nj)
                #pragma unroll
                for (int mi = 0; mi < 4; ++mi)
                    #pragma unroll
                    for (int j = 0; j < 4; ++j)
                        T[(wm + mi * 16 + g * 4 + j) * 72 + nj * 16 + r15] =
                            (f16)acc[mi][nj][j];
        }
        __syncthreads();
        #pragma unroll
        for (int q = 0; q < 4; ++q) {
            const int cid = q * 256 + tid;
            const int row = cid >> 3, c = (cid & 7) * 8;
            f16x8 v = *(const f16x8*)(T + row * 72 + c);
            f16* pdst = dst + (size_t)(m0 + row) * 1024 + n0 + p * 64 + c;
            f16x8 r = *(const f16x8*)pdst;
            f16x8 o2;
            #pragma unroll
            for (int e = 0; e < 8; ++e)
                o2[e] = (f16)((float)v[e] + (float)r[e]);
            *(f16x8*)pdst = o2;
        }
    }
}

// ---------------------------------------------------------------------------
// Flash attention with LDS-staged K/V tiles + double-buffered raw-barrier
// pipeline.  grid (64 bh, 8 qt).  Swapped QK^T; constant-shift exp;
// deferred row-sum; sigma' k-slot bijection on both PV operands.
// ---------------------------------------------------------------------------
__device__ __forceinline__ void attn_tile(
    const f16* KL, const f16* VL,
    const f16* Kn, const f16* Vn, f16* KLn, f16* VLn, bool doStage,
    const f16x8 qf[2][2], f32x4 o[2][4], f32x4 lsum[2], int g, int r15)
{
    f16x8 kf[4][2];
    #pragma unroll
    for (int nj = 0; nj < 4; ++nj)
        #pragma unroll
        for (int kc = 0; kc < 2; ++kc) {
            const int row = nj * 16 + r15;
            kf[nj][kc] = *(const f16x8*)(KL + row * 64 +
                                         (((kc * 4 + g) ^ (row & 7)) << 3));
        }
    f16x4 vlo[4][2], vhi[4][2];
    #pragma unroll
    for (int db = 0; db < 4; ++db)
        #pragma unroll
        for (int ch = 0; ch < 2; ++ch) {
            const int row = db * 16 + r15;
            const int c1 = ch * 4 + (g >> 1);
            const int c2 = c1 + 2;
            const int sub = (g & 1) * 4;
            vlo[db][ch] = *(const f16x4*)(VL + row * 64 +
                                          ((c1 ^ (row & 7)) << 3) + sub);
            vhi[db][ch] = *(const f16x4*)(VL + row * 64 +
                                          ((c2 ^ (row & 7)) << 3) + sub);
        }
    asm volatile("s_waitcnt lgkmcnt(0)" ::: "memory");
    __builtin_amdgcn_sched_barrier(0);
    __builtin_amdgcn_s_barrier();
    if (doStage) {
        stage64(Kn, 64, KLn);
        stage64(Vn, 1024, VLn);
    }
    __builtin_amdgcn_sched_barrier(0);
    f32x4 sacc[2][4] = {};
    #pragma unroll
    for (int nj = 0; nj < 4; ++nj)
        #pragma unroll
        for (int kc = 0; kc < 2; ++kc) {
            sacc[0][nj] = __builtin_amdgcn_mfma_f32_16x16x32_f16(
                kf[nj][kc], qf[0][kc], sacc[0][nj], 0, 0, 0);
            sacc[1][nj] = __builtin_amdgcn_mfma_f32_16x16x32_f16(
                kf[nj][kc], qf[1][kc], sacc[1][nj], 0, 0, 0);
        }
    #pragma unroll
    for (int qh = 0; qh < 2; ++qh) {
        f32x4 pe[4];
        #pragma unroll
        for (int nj = 0; nj < 4; ++nj) {
            #pragma unroll
            for (int j = 0; j < 4; ++j)
                pe[nj][j] = __expf(sacc[qh][nj][j] - 2.0f);
            lsum[qh] += pe[nj];
        }
        f16x8 pb[2];
        #pragma unroll
        for (int ch = 0; ch < 2; ++ch) {
            union { f16x2 h2[4]; f16x8 v8; } u;
            u.h2[0] = pkrtz(pe[2 * ch][0], pe[2 * ch][1]);
            u.h2[1] = pkrtz(pe[2 * ch][2], pe[2 * ch][3]);
            u.h2[2] = pkrtz(pe[2 * ch + 1][0], pe[2 * ch + 1][1]);
            u.h2[3] = pkrtz(pe[2 * ch + 1][2], pe[2 * ch + 1][3]);
            pb[ch] = u.v8;
        }
        #pragma unroll
        for (int db = 0; db < 4; ++db)
            #pragma unroll
            for (int ch = 0; ch < 2; ++ch) {
                union { f16x4 h4[2]; f16x8 v8; } w;
                w.h4[0] = vlo[db][ch];
                w.h4[1] = vhi[db][ch];
                o[qh][db] = __builtin_amdgcn_mfma_f32_16x16x32_f16(
                    w.v8, pb[ch], o[qh][db], 0, 0, 0);
            }
    }
    __builtin_amdgcn_sched_barrier(0);
    asm volatile("s_waitcnt vmcnt(0)" ::: "memory");
    __builtin_amdgcn_s_barrier();
}

__global__ __launch_bounds__(256) void k_attn(
    const f16* __restrict__ qn, const f16* __restrict__ kn,
    const f16* __restrict__ vT, f16* __restrict__ ctx)
{
    __shared__ __align__(16) f16 lds[4][4096];   // K0 V0 K1 V1
    const int bh = blockIdx.x, b = bh >> 4, h = bh & 15;
    const f16* Qp = qn + (size_t)b * 1048576 + h * 65536;
    const f16* Kp = kn + (size_t)b * 1048576 + h * 65536;
    const f16* Vp = vT + (size_t)b * 1048576 + h * 65536;
    const int tid = threadIdx.x, lid = tid & 63, wv = tid >> 6;
    const int g = lid >> 4, r15 = lid & 15;
    const int q0 = blockIdx.y * 128 + wv * 32;

    f16x8 qf[2][2];
    #pragma unroll
    for (int qh = 0; qh < 2; ++qh)
        #pragma unroll
        for (int kc = 0; kc < 2; ++kc) {
            f16x8 t = *(const f16x8*)(Qp + (q0 + qh * 16 + r15) * 64 + kc * 32 + g * 8);
            #pragma unroll
            for (int e = 0; e < 8; ++e) t[e] = t[e] * (f16)0.125f;
            qf[qh][kc] = t;
        }

    f32x4 o[2][4] = {};
    f32x4 lsum[2] = {};

    stage64(Kp, 64, lds[0]);
    stage64(Vp, 1024, lds[1]);
    asm volatile("s_waitcnt vmcnt(0)" ::: "memory");
    __builtin_amdgcn_s_barrier();

    for (int tt = 0; tt < 8; ++tt) {
        const int t1 = 2 * tt + 1;
        attn_tile(lds[0], lds[1], Kp + t1 * 4096, Vp + t1 * 64,
                  lds[2], lds[3], true, qf, o, lsum, g, r15);
        attn_tile(lds[2], lds[3], Kp + (t1 + 1) * 4096, Vp + (t1 + 1) * 64,
                  lds[0], lds[1], tt < 7, qf, o, lsum, g, r15);
    }

    float inv[2];
    #pragma unroll
    for (int qh = 0; qh < 2; ++qh) {
        float lr = lsum[qh][0] + lsum[qh][1] + lsum[qh][2] + lsum[qh][3];
        lr += __shfl_xor(lr, 16);
        lr += __shfl_xor(lr, 32);
        inv[qh] = 1.0f / lr;
    }
    f16* Olds = &lds[0][0] + wv * (32 * 72);
    #pragma unroll
    for (int qh = 0; qh < 2; ++qh)
        #pragma unroll
        for (int db = 0; db < 4; ++db) {
            const int row = qh * 16 + r15, col = db * 16 + g * 4;
            *(f16x2*)(Olds + row * 72 + col) =
                pkrtz(o[qh][db][0] * inv[qh], o[qh][db][1] * inv[qh]);
            *(f16x2*)(Olds + row * 72 + col + 2) =
                pkrtz(o[qh][db][2] * inv[qh], o[qh][db][3] * inv[qh]);
        }
    asm volatile("s_waitcnt lgkmcnt(0)" ::: "memory");
    __builtin_amdgcn_sched_barrier(0);
    #pragma unroll
    for (int p = 0; p < 4; ++p) {
        const int row = p * 8 + (lid >> 3);
        const int c8 = (lid & 7) * 8;
        f16x8 v = *(const f16x8*)(Olds + row * 72 + c8);
        *(f16x8*)(ctx + (size_t)b * 1048576 + (q0 + row) * 1024 + h * 64 + c8) = v;
    }
}

// ---------------------------------------------------------------------------
// Final GEMM: out = ctx @ Wfc + bfc, output FLOAT32.  Chunked XCD swizzle.
// ---------------------------------------------------------------------------
__global__ __launch_bounds__(256) void k_gemm_final(
    const f16* __restrict__ ctx, const f16* __restrict__ WFt,
    const float* __restrict__ bfc, float* __restrict__ out)
{
    __shared__ __align__(16) f16 smem[16384];
    const int nid = blockIdx.x + blockIdx.y * 8;
    const int wgid = (nid & 7) * 32 + (nid >> 3);      // bijective, 256=8*32
    const int xw = wgid & 7, yw = wgid >> 3;
    const int m0 = yw * 128, n0 = xw * 128;
    f32x4 acc[4][4] = {};
    gemm_core64<0>(ctx, 1024, m0, WFt + n0 * 1024, 1024, 1024,
                   smem, smem + 8192, acc);

    const int tid = threadIdx.x, lid = tid & 63, wv = tid >> 6;
    const int wm = (wv >> 1) * 64, wn = (wv & 1) * 64, g = lid >> 4, r15 = lid & 15;
    #pragma unroll
    for (int nj = 0; nj < 4; ++nj) {
        const int col = n0 + wn + nj * 16 + r15;
        const float bv = bfc[col];
        #pragma unroll
        for (int mi = 0; mi < 4; ++mi)
            #pragma unroll
            for (int j = 0; j < 4; ++j) {
                const int row = m0 + wm + mi * 16 + g * 4 + j;
                out[(size_t)row * 1024 + col] = acc[mi][nj][j] + bv;
            }
    }
}

// ---------------------------------------------------------------------------
// Workspace (64 MiB), round-15 layout:
//   qx4 @0  kx4 @8M  vT @16M  WFt @24M (live: proj..final)
//   Qh @26M  Kh @34M  Vh @42M  WQt @50M  WKt @52M  WVt @54M  CTq @56M
//   After proj: XtQ @26M  XtK @34.03M  CTk @42.05M (over dead Vh/WQt)
//   After conv: ctxb @26M over dead XtQ (attn -> final)
//   ORDER: k_mid (ctrans part) AFTER k_gemm_proj (CTk overlays Vh/WQt).
// ---------------------------------------------------------------------------
extern "C" void kernel_launch(void* const* d_in, const int* in_sizes, int n_in,
                              void* d_out, int out_size, void* d_ws, size_t ws_size,
                              hipStream_t stream)
{
    (void)in_sizes; (void)n_in; (void)out_size; (void)ws_size;
    const float* Q     = (const float*)d_in[0];
    const float* K     = (const float*)d_in[1];
    const float* V     = (const float*)d_in[2];
    // d_in[3] = attn_mask (unused by reference)
    const float* WQ    = (const float*)d_in[4];
    const float* bQ    = (const float*)d_in[5];
    const float* WK    = (const float*)d_in[6];
    const float* bK    = (const float*)d_in[7];
    const float* WV    = (const float*)d_in[8];
    const float* bV    = (const float*)d_in[9];
    const float* Wfc   = (const float*)d_in[10];
    const float* bfc   = (const float*)d_in[11];
    const float* convq = (const float*)d_in[12];
    const float* convk = (const float*)d_in[13];
    const float* w     = (const float*)d_in[14];

    char* ws = (char*)d_ws;
    f16* qx4   = (f16*)(ws + 0);
    f16* kx4   = (f16*)(ws + 8388608);
    f16* vT    = (f16*)(ws + 16777216);
    f16* WFt   = (f16*)(ws + 25165824);
    f16* Qh    = (f16*)(ws + 27262976);
    f16* Kh    = (f16*)(ws + 35651584);
    f16* Vh    = (f16*)(ws + 44040192);
    f16* WQt   = (f16*)(ws + 52428800);
    f16* WKt   = (f16*)(ws + 54525952);
    f16* WVt   = (f16*)(ws + 56623104);
    f16* CTq   = (f16*)(ws + 58720256);
    f16* XtQ   = (f16*)(ws + 27262976);  // over dead Qh (+Kh head)
    f16* XtK   = (f16*)(ws + 35676160);  // over dead Kh (+Vh head)
    f16* CTk   = (f16*)(ws + 44089344);  // over dead Vh (+WQt head) - AFTER proj!
    f16* ctxb  = (f16*)(ws + 27262976);  // over dead XtQ (attn->final)

    dim3 b256(256);

    // 1) merged preproc: cvt Q/K/V + weight transposes
    k_pre<<<16384, b256, 0, stream>>>(Q, K, V, WQ, WK, WV, Wfc,
                                      Qh, Kh, Vh, WQt, WKt, WVt, WFt);
    // 2) projections (64x128 tiles; xw-fast swizzle)
    k_gemm_proj<<<dim3(8, 64, 3), b256, 0, stream>>>(Qh, Kh, Vh, WQt, WKt, WVt,
                                                     bQ, bK, bV, qx4, kx4, vT);
    // 3) merged preproc 2: conv-weight transposes + Xt transpose-pad
    k_mid<<<16640, b256, 0, stream>>>(convq, convk, CTq, CTk,
                                      qx4, kx4, XtQ, XtK);
    // 4) fused conv GEMM + residual (128x128 tiles, z-per-XCD swizzle)
    k_gemm_conv<<<dim3(8, 8, 8), b256, 0, stream>>>(XtQ, XtK, CTq, CTk,
                                                    qx4, kx4, w);
    // 5) flash attention -> ctx (LDS-staged K/V; XCD-friendly grid x=bh)
    k_attn<<<dim3(64, 8), b256, 0, stream>>>(qx4, kx4, vT, ctxb);
    // 6) final projection -> f32 output (chunked swizzle)
    k_gemm_final<<<dim3(8, 32), b256, 0, stream>>>(ctxb, WFt, bfc, (float*)d_out);
}

// Round 20
// 161.228 us; speedup vs baseline: 1.1988x; 1.0122x over previous
//
#include <hip/hip_runtime.h>
#include <hip/hip_bf16.h>

typedef _Float16 f16;
typedef _Float16 f16x2 __attribute__((ext_vector_type(2)));
typedef _Float16 f16x4 __attribute__((ext_vector_type(4)));
typedef _Float16 f16x8 __attribute__((ext_vector_type(8)));
typedef float f32x4 __attribute__((ext_vector_type(4)));

// cvt_pkrtz returns __fp16 ext_vector(2); re-cast to our f16x2 (same bits).
__device__ __forceinline__ f16x2 pkrtz(float a, float b) {
    auto r = __builtin_amdgcn_cvt_pkrtz(a, b);
    f16x2 o; o[0] = (f16)r[0]; o[1] = (f16)r[1];
    return o;
}

#define XT_ROWS 1027
#define XT_BSTRIDE (XT_ROWS * 1024)   // elems per batch

// ---------------------------------------------------------------------------
// global -> LDS direct (16B per lane, wave-uniform LDS base + lane*16)
// ---------------------------------------------------------------------------
__device__ __forceinline__ void gload16(const f16* g, f16* l) {
    __builtin_amdgcn_global_load_lds(
        (const __attribute__((address_space(1))) void*)g,
        (__attribute__((address_space(3))) void*)l, 16, 0, 0);
}

// ---------------------------------------------------------------------------
// Stage a 128x64 f16 tile (16KB).  XOR-swizzle on SOURCE col; same XOR on
// the read side (involution) -> conflict-free ds_read_b128.
// ---------------------------------------------------------------------------
__device__ __forceinline__ void stage_tile(const f16* src, int ld, f16* lds)
{
    const int tid = threadIdx.x;
    const int w512 = (tid >> 6) << 9;          // wave base (f16 elems)
    #pragma unroll
    for (int q = 0; q < 4; ++q) {
        const int s = q * 256 + tid;           // 16B slot id, 0..1023
        const int row = s >> 3;
        const int col = ((s & 7) ^ (row & 7)) << 3;
        gload16(src + row * ld + col, lds + (q << 11) + w512);
    }
}

// ---------------------------------------------------------------------------
// Stage a 64x64 f16 tile (8KB) the same way (512 slots, 2 per thread).
// ---------------------------------------------------------------------------
__device__ __forceinline__ void stage64(const f16* src, int ld, f16* lds)
{
    const int tid = threadIdx.x;
    const int w512 = (tid >> 6) << 9;
    #pragma unroll
    for (int q = 0; q < 2; ++q) {
        const int s = q * 256 + tid;           // 16B slot id, 0..511
        const int row = s >> 3;
        const int col = ((s & 7) ^ (row & 7)) << 3;
        gload16(src + row * ld + col, lds + (q << 11) + w512);
    }
}

// ---------------------------------------------------------------------------
// GEMM core 128x128 (proven 2-barrier structure).
// CONV=1: A row base = m0 + (k0>>10) into zero-padded Xt, col = k0&1023.
// ---------------------------------------------------------------------------
template <int CONV>
__device__ __forceinline__ void gemm_core64(
    const f16* __restrict__ A, int lda, int m0,
    const f16* __restrict__ Bt, int ldb, int K,
    f16* Alds, f16* Blds, f32x4 acc[4][4])
{
    const int tid = threadIdx.x;
    const int lid = tid & 63;
    const int wv  = tid >> 6;
    const int wm  = (wv >> 1) * 64;
    const int wn  = (wv & 1) * 64;
    const int g   = lid >> 4;
    const int r15 = lid & 15;

    stage_tile(A + m0 * lda, lda, Alds);
    stage_tile(Bt, ldb, Blds);
    asm volatile("s_waitcnt vmcnt(0)" ::: "memory");
    __builtin_amdgcn_s_barrier();

    for (int k0 = 0; k0 < K; k0 += 64) {
        f16x8 af[2][4], bf[2][4];
        #pragma unroll
        for (int kc = 0; kc < 2; ++kc) {
            #pragma unroll
            for (int mi = 0; mi < 4; ++mi) {
                const int row = wm + mi * 16 + r15;
                af[kc][mi] = *(const f16x8*)(Alds + row * 64 +
                                             (((kc * 4 + g) ^ (row & 7)) << 3));
            }
            #pragma unroll
            for (int nj = 0; nj < 4; ++nj) {
                const int row = wn + nj * 16 + r15;
                bf[kc][nj] = *(const f16x8*)(Blds + row * 64 +
                                             (((kc * 4 + g) ^ (row & 7)) << 3));
            }
        }
        asm volatile("s_waitcnt lgkmcnt(0)" ::: "memory");
        __builtin_amdgcn_sched_barrier(0);
        __builtin_amdgcn_s_barrier();
        const int k1 = k0 + 64;
        if (k1 < K) {
            const f16* Asrc;
            if (CONV) Asrc = A + (m0 + (k1 >> 10)) * lda + (k1 & 1023);
            else      Asrc = A + m0 * lda + k1;
            stage_tile(Asrc, lda, Alds);
            stage_tile(Bt + k1, ldb, Blds);
        }
        __builtin_amdgcn_sched_barrier(0);
        #pragma unroll
        for (int kc = 0; kc < 2; ++kc)
            #pragma unroll
            for (int mi = 0; mi < 4; ++mi)
                #pragma unroll
                for (int nj = 0; nj < 4; ++nj)
                    acc[mi][nj] = __builtin_amdgcn_mfma_f32_16x16x32_f16(
                        af[kc][mi], bf[kc][nj], acc[mi][nj], 0, 0, 0);
        __builtin_amdgcn_sched_barrier(0);
        asm volatile("s_waitcnt vmcnt(0)" ::: "memory");
        __builtin_amdgcn_s_barrier();
    }
}

// ---------------------------------------------------------------------------
// GEMM core 64x128 (small tile, 24KB LDS).  Waves 2x2: wave tile 32x64.
// ---------------------------------------------------------------------------
template <int CONV>
__device__ __forceinline__ void gemm_core_s(
    const f16* __restrict__ A, int lda, int m0,
    const f16* __restrict__ Bt, int ldb, int K,
    f16* Alds, f16* Blds, f32x4 acc[2][4])
{
    const int tid = threadIdx.x;
    const int lid = tid & 63;
    const int wv  = tid >> 6;
    const int wm  = (wv >> 1) * 32;
    const int wn  = (wv & 1) * 64;
    const int g   = lid >> 4;
    const int r15 = lid & 15;

    stage64(A + m0 * lda, lda, Alds);
    stage_tile(Bt, ldb, Blds);
    asm volatile("s_waitcnt vmcnt(0)" ::: "memory");
    __builtin_amdgcn_s_barrier();

    for (int k0 = 0; k0 < K; k0 += 64) {
        f16x8 af[2][2], bf[2][4];
        #pragma unroll
        for (int kc = 0; kc < 2; ++kc) {
            #pragma unroll
            for (int mi = 0; mi < 2; ++mi) {
                const int row = wm + mi * 16 + r15;
                af[kc][mi] = *(const f16x8*)(Alds + row * 64 +
                                             (((kc * 4 + g) ^ (row & 7)) << 3));
            }
            #pragma unroll
            for (int nj = 0; nj < 4; ++nj) {
                const int row = wn + nj * 16 + r15;
                bf[kc][nj] = *(const f16x8*)(Blds + row * 64 +
                                             (((kc * 4 + g) ^ (row & 7)) << 3));
            }
        }
        asm volatile("s_waitcnt lgkmcnt(0)" ::: "memory");
        __builtin_amdgcn_sched_barrier(0);
        __builtin_amdgcn_s_barrier();
        const int k1 = k0 + 64;
        if (k1 < K) {
            const f16* Asrc;
            if (CONV) Asrc = A + (m0 + (k1 >> 10)) * lda + (k1 & 1023);
            else      Asrc = A + m0 * lda + k1;
            stage64(Asrc, lda, Alds);
            stage_tile(Bt + k1, ldb, Blds);
        }
        __builtin_amdgcn_sched_barrier(0);
        #pragma unroll
        for (int kc = 0; kc < 2; ++kc)
            #pragma unroll
            for (int mi = 0; mi < 2; ++mi)
                #pragma unroll
                for (int nj = 0; nj < 4; ++nj)
                    acc[mi][nj] = __builtin_amdgcn_mfma_f32_16x16x32_f16(
                        af[kc][mi], bf[kc][nj], acc[mi][nj], 0, 0, 0);
        __builtin_amdgcn_sched_barrier(0);
        asm volatile("s_waitcnt vmcnt(0)" ::: "memory");
        __builtin_amdgcn_s_barrier();
    }
}

// ---------------------------------------------------------------------------
// Merged preproc 1: cvt Q/K/V (blocks 0..12287) + weight transposes
// (blocks 12288..16383; 1024 blocks per weight).
// ---------------------------------------------------------------------------
__global__ __launch_bounds__(256) void k_pre(
    const float* __restrict__ Q, const float* __restrict__ K,
    const float* __restrict__ V,
    const float* __restrict__ WQ, const float* __restrict__ WK,
    const float* __restrict__ WV, const float* __restrict__ Wfc,
    f16* __restrict__ Qh, f16* __restrict__ Kh, f16* __restrict__ Vh,
    f16* __restrict__ WQt, f16* __restrict__ WKt,
    f16* __restrict__ WVt, f16* __restrict__ WFt)
{
    __shared__ float tile[32][33];
    const int bid = blockIdx.x, tid = threadIdx.x;
    if (bid < 12288) {
        const int which = bid >> 12;
        const int i = (bid & 4095) * 256 + tid;
        const float* in = which == 0 ? Q : which == 1 ? K : V;
        f16* out = which == 0 ? Qh : which == 1 ? Kh : Vh;
        float4 v = ((const float4*)in)[i];
        f16x4 o;
        o[0] = (f16)v.x; o[1] = (f16)v.y; o[2] = (f16)v.z; o[3] = (f16)v.w;
        ((f16x4*)out)[i] = o;
    } else {
        const int wb = bid - 12288;
        const int z = wb >> 10;
        const int xy = wb & 1023;
        const int c0 = (xy & 31) * 32, r0 = (xy >> 5) * 32;
        const float* in = z == 0 ? WQ : z == 1 ? WK : z == 2 ? WV : Wfc;
        f16* out = z == 0 ? WQt : z == 1 ? WKt : z == 2 ? WVt : WFt;
        const int tx = tid & 31, ty = tid >> 5;
        #pragma unroll
        for (int i = ty; i < 32; i += 8)
            tile[i][tx] = in[(size_t)(r0 + i) * 1024 + c0 + tx];
        __syncthreads();
        #pragma unroll
        for (int i = ty; i < 32; i += 8)
            out[(size_t)(c0 + i) * 1024 + r0 + tx] = (f16)tile[tx][i];
    }
}

// ---------------------------------------------------------------------------
// Merged preproc 2 (AFTER proj — CTk overlays dead Vh/WQt):
// conv-weight transposes (blocks 0..8191) + Xt transpose-pad (8192..16639).
// ---------------------------------------------------------------------------
__global__ __launch_bounds__(256) void k_mid(
    const float* __restrict__ convq, const float* __restrict__ convk,
    f16* __restrict__ CTq, f16* __restrict__ CTk,
    const f16* __restrict__ qx4, const f16* __restrict__ kx4,
    f16* __restrict__ XtQ, f16* __restrict__ XtK)
{
    __shared__ __align__(16) float tbuf[32][33];
    const int bid = blockIdx.x, tid = threadIdx.x;
    const int tx = tid & 31, ty = tid >> 5;
    if (bid < 8192) {
        const int z = bid >> 12;
        const int xy = bid & 4095;
        const int c0 = (xy & 127) * 32, r0 = (xy >> 7) * 32;
        const float* in = z ? convk : convq;
        f16* out = z ? CTk : CTq;
        #pragma unroll
        for (int i = ty; i < 32; i += 8)
            tbuf[i][tx] = in[(size_t)(r0 + i) * 4096 + c0 + tx];
        __syncthreads();
        #pragma unroll
        for (int i = ty; i < 32; i += 8)
            out[(size_t)(c0 + i) * 1024 + r0 + tx] = (f16)tbuf[tx][i];
    } else {
        const int pb = bid - 8192;
        const int z = pb / 1056, rem = pb % 1056;
        const int b = z & 3, ten = z >> 2;
        const int c0 = (rem & 31) * 32;
        const int tp0 = (rem >> 5) * 32;
        const f16* in = (ten ? kx4 : qx4) + (size_t)b * 1048576;
        f16* out = (ten ? XtK : XtQ) + (size_t)b * XT_BSTRIDE;
        f16* tile = (f16*)tbuf;             // [32][33] f16
        #pragma unroll
        for (int i = ty; i < 32; i += 8) {
            int t = tp0 + tx - 2;
            tile[i * 33 + tx] = (t >= 0 && t < 1024)
                                ? in[(c0 + i) * 1024 + t] : (f16)0.f;
        }
        __syncthreads();
        #pragma unroll
        for (int i = ty; i < 32; i += 8) {
            int tp = tp0 + i;
            if (tp < XT_ROWS) out[tp * 1024 + c0 + tx] = tile[tx * 33 + i];
        }
    }
}

// ---------------------------------------------------------------------------
// Projection GEMMs, 64x128 tiles (1536 blocks).  XCD-chunked swizzle with
// xw FAST: B L2-resident, A panels hot.  z=0: q ; z=1: k ; z=2: v -> vT.
// ---------------------------------------------------------------------------
__global__ __launch_bounds__(256) void k_gemm_proj(
    const f16* __restrict__ Qh, const f16* __restrict__ Kh, const f16* __restrict__ Vh,
    const f16* __restrict__ WQt, const f16* __restrict__ WKt, const f16* __restrict__ WVt,
    const float* __restrict__ bQ, const float* __restrict__ bK, const float* __restrict__ bV,
    f16* __restrict__ qx4, f16* __restrict__ kx4, f16* __restrict__ vT)
{
    __shared__ __align__(16) f16 smem[12288];   // A 8KB @0, B 16KB @4096
    const int nid = blockIdx.x + blockIdx.y * 8 + blockIdx.z * 512;
    const int wgid = (nid & 7) * 192 + (nid >> 3);     // bijective, 1536=8*192
    const int z = wgid >> 9, rem = wgid & 511;
    const int xw = rem & 7, yw = rem >> 3;             // xw fast -> B resident
    const f16* A  = z == 0 ? Qh : z == 1 ? Kh : Vh;
    const f16* Bt = z == 0 ? WQt : z == 1 ? WKt : WVt;
    const float* bias = z == 0 ? bQ : z == 1 ? bK : bV;
    f16* dst = z == 0 ? qx4 : z == 1 ? kx4 : vT;
    const int m0 = yw * 64, n0 = xw * 128;
    f32x4 acc[2][4] = {};
    gemm_core_s<0>(A, 1024, m0, Bt + n0 * 1024, 1024, 1024,
                   smem, smem + 4096, acc);

    const int tid = threadIdx.x, lid = tid & 63, wv = tid >> 6;
    const int wm = (wv >> 1) * 32, g = lid >> 4, r15 = lid & 15;
    f16* T = smem;                        // [64][72] = 9216B
    #pragma unroll
    for (int p = 0; p < 2; ++p) {
        __syncthreads();
        if ((wv & 1) == p) {
            #pragma unroll
            for (int nj = 0; nj < 4; ++nj) {
                const int col = n0 + p * 64 + nj * 16 + r15;
                const float bv = bias[col];
                #pragma unroll
                for (int mi = 0; mi < 2; ++mi)
                    #pragma unroll
                    for (int j = 0; j < 4; ++j)
                        T[(wm + mi * 16 + g * 4 + j) * 72 + nj * 16 + r15] =
                            (f16)(acc[mi][nj][j] + bv);
            }
        }
        __syncthreads();
        const int h = (n0 + p * 64) >> 6;
        if (z != 2) {
            #pragma unroll
            for (int q = 0; q < 2; ++q) {
                const int cid = q * 256 + tid;        // 0..511
                const int row = cid >> 3, c = (cid & 7) * 8;
                f16x8 v = *(const f16x8*)(T + row * 72 + c);
                const int grow = m0 + row;
                const int b = grow >> 10, l = grow & 1023;
                *(f16x8*)(dst + b * 1048576 + h * 65536 + l * 64 + c) = v;
            }
        } else {
            const int b = m0 >> 10, l0 = m0 & 1023;
            #pragma unroll
            for (int q = 0; q < 2; ++q) {
                const int cid = q * 256 + tid;        // 0..511
                const int d = cid >> 3, lc = (cid & 7) * 8;
                f16x8 v;
                #pragma unroll
                for (int e = 0; e < 8; ++e) v[e] = T[(lc + e) * 72 + d];
                *(f16x8*)(dst + b * 1048576 + h * 65536 + d * 1024 + l0 + lc) = v;
            }
        }
    }
}

// ---------------------------------------------------------------------------
// Fused conv GEMM + residual, 128x128 tiles (512 blocks, z-per-XCD swizzle;
// yw fast inner so CT tile hot, A Xt 2MB L2-resident).
// ---------------------------------------------------------------------------
__global__ __launch_bounds__(256) void k_gemm_conv(
    const f16* __restrict__ XtQ, const f16* __restrict__ XtK,
    const f16* __restrict__ CTq, const f16* __restrict__ CTk,
    f16* __restrict__ qx4, f16* __restrict__ kx4,
    const float* __restrict__ wvec)
{
    __shared__ __align__(16) f16 smem[16384];
    const int nid = blockIdx.x + blockIdx.y * 8 + blockIdx.z * 64;
    const int z = nid & 7;                 // XCD-resident (tensor,batch)
    const int inner = nid >> 3;            // 0..63
    const int yw = inner & 7;              // m-tile (fast; A cycles in L2)
    const int xw = inner >> 3;             // n-tile (slow; CT tile hot)
    const int b = z & 3, ten = z >> 2;
    const f16* Xt = (ten ? XtK : XtQ) + (size_t)b * XT_BSTRIDE;
    const f16* CT = ten ? CTk : CTq;
    f16* dst = (ten ? kx4 : qx4) + (size_t)b * 1048576;

    const int flen = (2.f * wvec[0] >= 4.f * wvec[1]) ? 2 : 4;
    const int K = flen << 10;

    const int m0 = yw * 128, n0 = xw * 128;
    f32x4 acc[4][4] = {};
    gemm_core64<1>(Xt, 1024, m0, CT + n0 * 4096, 4096, K,
                   smem, smem + 8192, acc);

    const int tid = threadIdx.x, lid = tid & 63, wv = tid >> 6;
    const int wm = (wv >> 1) * 64, g = lid >> 4, r15 = lid & 15;
    f16* T = smem;
    #pragma unroll
    for (int p = 0; p < 2; ++p) {
        __syncthreads();
        if ((wv & 1) == p) {
            #pragma unroll
            for (int nj = 0; nj < 4; ++nj)
                #pragma unroll
                for (int mi = 0; mi < 4; ++mi)
                    #pragma unroll
                    for (int j = 0; j < 4; ++j)
                        T[(wm + mi * 16 + g * 4 + j) * 72 + nj * 16 + r15] =
                            (f16)acc[mi][nj][j];
        }
        __syncthreads();
        #pragma unroll
        for (int q = 0; q < 4; ++q) {
            const int cid = q * 256 + tid;
            const int row = cid >> 3, c = (cid & 7) * 8;
            f16x8 v = *(const f16x8*)(T + row * 72 + c);
            f16* pdst = dst + (size_t)(m0 + row) * 1024 + n0 + p * 64 + c;
            f16x8 r = *(const f16x8*)pdst;
            f16x8 o2;
            #pragma unroll
            for (int e = 0; e < 8; ++e)
                o2[e] = (f16)((float)v[e] + (float)r[e]);
            *(f16x8*)pdst = o2;
        }
    }
}

// ---------------------------------------------------------------------------
// Flash attention, KVBLK=128, ONE barrier + ONE vmcnt drain per KV step.
// Double-buffered 64KB LDS (2 x (16KB K + 16KB V), 64x64 chunks).
// Invariant: stage into buf[nxt] is safe without a pre-barrier because all
// waves' ds_reads of buf[nxt] completed (per-wave lgkmcnt(0)) before the
// previous end-of-step barrier.  grid (64 bh, 8 qt); swapped QK^T;
// constant-shift exp; deferred row-sum; sigma' k-slot bijection.
// ---------------------------------------------------------------------------
__device__ __forceinline__ void attn_chunk(
    const f16* KL, const f16* VL,
    const f16x8 qf[2][2], f32x4 o[2][4], f32x4 lsum[2], int g, int r15)
{
    f16x8 kf[4][2];
    #pragma unroll
    for (int nj = 0; nj < 4; ++nj)
        #pragma unroll
        for (int kc = 0; kc < 2; ++kc) {
            const int row = nj * 16 + r15;
            kf[nj][kc] = *(const f16x8*)(KL + row * 64 +
                                         (((kc * 4 + g) ^ (row & 7)) << 3));
        }
    f16x4 vlo[4][2], vhi[4][2];
    #pragma unroll
    for (int db = 0; db < 4; ++db)
        #pragma unroll
        for (int ch = 0; ch < 2; ++ch) {
            const int row = db * 16 + r15;
            const int c1 = ch * 4 + (g >> 1);
            const int c2 = c1 + 2;
            const int sub = (g & 1) * 4;
            vlo[db][ch] = *(const f16x4*)(VL + row * 64 +
                                          ((c1 ^ (row & 7)) << 3) + sub);
            vhi[db][ch] = *(const f16x4*)(VL + row * 64 +
                                          ((c2 ^ (row & 7)) << 3) + sub);
        }
    asm volatile("s_waitcnt lgkmcnt(0)" ::: "memory");
    __builtin_amdgcn_sched_barrier(0);
    f32x4 sacc[2][4] = {};
    #pragma unroll
    for (int nj = 0; nj < 4; ++nj)
        #pragma unroll
        for (int kc = 0; kc < 2; ++kc) {
            sacc[0][nj] = __builtin_amdgcn_mfma_f32_16x16x32_f16(
                kf[nj][kc], qf[0][kc], sacc[0][nj], 0, 0, 0);
            sacc[1][nj] = __builtin_amdgcn_mfma_f32_16x16x32_f16(
                kf[nj][kc], qf[1][kc], sacc[1][nj], 0, 0, 0);
        }
    #pragma unroll
    for (int qh = 0; qh < 2; ++qh) {
        f32x4 pe[4];
        #pragma unroll
        for (int nj = 0; nj < 4; ++nj) {
            #pragma unroll
            for (int j = 0; j < 4; ++j)
                pe[nj][j] = __expf(sacc[qh][nj][j] - 2.0f);
            lsum[qh] += pe[nj];
        }
        f16x8 pb[2];
        #pragma unroll
        for (int ch = 0; ch < 2; ++ch) {
            union { f16x2 h2[4]; f16x8 v8; } u;
            u.h2[0] = pkrtz(pe[2 * ch][0], pe[2 * ch][1]);
            u.h2[1] = pkrtz(pe[2 * ch][2], pe[2 * ch][3]);
            u.h2[2] = pkrtz(pe[2 * ch + 1][0], pe[2 * ch + 1][1]);
            u.h2[3] = pkrtz(pe[2 * ch + 1][2], pe[2 * ch + 1][3]);
            pb[ch] = u.v8;
        }
        #pragma unroll
        for (int db = 0; db < 4; ++db)
            #pragma unroll
            for (int ch = 0; ch < 2; ++ch) {
                union { f16x4 h4[2]; f16x8 v8; } w;
                w.h4[0] = vlo[db][ch];
                w.h4[1] = vhi[db][ch];
                o[qh][db] = __builtin_amdgcn_mfma_f32_16x16x32_f16(
                    w.v8, pb[ch], o[qh][db], 0, 0, 0);
            }
    }
}

__global__ __launch_bounds__(256) void k_attn(
    const f16* __restrict__ qn, const f16* __restrict__ kn,
    const f16* __restrict__ vT, f16* __restrict__ ctx)
{
    // buffer b: K chunks at [b*4+0],[b*4+1]; V chunks at [b*4+2],[b*4+3]
    __shared__ __align__(16) f16 lds[8][4096];
    const int bh = blockIdx.x, b = bh >> 4, h = bh & 15;
    const f16* Qp = qn + (size_t)b * 1048576 + h * 65536;
    const f16* Kp = kn + (size_t)b * 1048576 + h * 65536;
    const f16* Vp = vT + (size_t)b * 1048576 + h * 65536;
    const int tid = threadIdx.x, lid = tid & 63, wv = tid >> 6;
    const int g = lid >> 4, r15 = lid & 15;
    const int q0 = blockIdx.y * 128 + wv * 32;

    f16x8 qf[2][2];
    #pragma unroll
    for (int qh = 0; qh < 2; ++qh)
        #pragma unroll
        for (int kc = 0; kc < 2; ++kc) {
            f16x8 t = *(const f16x8*)(Qp + (q0 + qh * 16 + r15) * 64 + kc * 32 + g * 8);
            #pragma unroll
            for (int e = 0; e < 8; ++e) t[e] = t[e] * (f16)0.125f;
            qf[qh][kc] = t;
        }

    f32x4 o[2][4] = {};
    f32x4 lsum[2] = {};

    // prologue: stage KV step 0 (rows 0..127) into buffer 0
    stage64(Kp, 64, lds[0]);
    stage64(Kp + 64 * 64, 64, lds[1]);
    stage64(Vp, 1024, lds[2]);
    stage64(Vp + 64, 1024, lds[3]);
    asm volatile("s_waitcnt vmcnt(0)" ::: "memory");
    __builtin_amdgcn_s_barrier();

    for (int t = 0; t < 8; ++t) {
        const int cur = (t & 1) * 4;
        const int nxt = 4 - cur;
        if (t < 7) {
            const int kv1 = (t + 1) * 128;
            stage64(Kp + kv1 * 64, 64, lds[nxt + 0]);
            stage64(Kp + (kv1 + 64) * 64, 64, lds[nxt + 1]);
            stage64(Vp + kv1, 1024, lds[nxt + 2]);
            stage64(Vp + kv1 + 64, 1024, lds[nxt + 3]);
        }
        __builtin_amdgcn_sched_barrier(0);
        attn_chunk(lds[cur + 0], lds[cur + 2], qf, o, lsum, g, r15);
        __builtin_amdgcn_sched_barrier(0);
        attn_chunk(lds[cur + 1], lds[cur + 3], qf, o, lsum, g, r15);
        __builtin_amdgcn_sched_barrier(0);
        asm volatile("s_waitcnt vmcnt(0)" ::: "memory");
        __builtin_amdgcn_s_barrier();
    }

    float inv[2];
    #pragma unroll
    for (int qh = 0; qh < 2; ++qh) {
        float lr = lsum[qh][0] + lsum[qh][1] + lsum[qh][2] + lsum[qh][3];
        lr += __shfl_xor(lr, 16);
        lr += __shfl_xor(lr, 32);
        inv[qh] = 1.0f / lr;
    }
    f16* Olds = &lds[0][0] + wv * (32 * 72);
    #pragma unroll
    for (int qh = 0; qh < 2; ++qh)
        #pragma unroll
        for (int db = 0; db < 4; ++db) {
            const int row = qh * 16 + r15, col = db * 16 + g * 4;
            *(f16x2*)(Olds + row * 72 + col) =
                pkrtz(o[qh][db][0] * inv[qh], o[qh][db][1] * inv[qh]);
            *(f16x2*)(Olds + row * 72 + col + 2) =
                pkrtz(o[qh][db][2] * inv[qh], o[qh][db][3] * inv[qh]);
        }
    asm volatile("s_waitcnt lgkmcnt(0)" ::: "memory");
    __builtin_amdgcn_sched_barrier(0);
    #pragma unroll
    for (int p = 0; p < 4; ++p) {
        const int row = p * 8 + (lid >> 3);
        const int c8 = (lid & 7) * 8;
        f16x8 v = *(const f16x8*)(Olds + row * 72 + c8);
        *(f16x8*)(ctx + (size_t)b * 1048576 + (q0 + row) * 1024 + h * 64 + c8) = v;
    }
}

// ---------------------------------------------------------------------------
// Final GEMM: out = ctx @ Wfc + bfc, output FLOAT32.  Chunked XCD swizzle.
// ---------------------------------------------------------------------------
__global__ __launch_bounds__(256) void k_gemm_final(
    const f16* __restrict__ ctx, const f16* __restrict__ WFt,
    const float* __restrict__ bfc, float* __restrict__ out)
{
    __shared__ __align__(16) f16 smem[16384];
    const int nid = blockIdx.x + blockIdx.y * 8;
    const int wgid = (nid & 7) * 32 + (nid >> 3);      // bijective, 256=8*32
    const int xw = wgid & 7, yw = wgid >> 3;
    const int m0 = yw * 128, n0 = xw * 128;
    f32x4 acc[4][4] = {};
    gemm_core64<0>(ctx, 1024, m0, WFt + n0 * 1024, 1024, 1024,
                   smem, smem + 8192, acc);

    const int tid = threadIdx.x, lid = tid & 63, wv = tid >> 6;
    const int wm = (wv >> 1) * 64, wn = (wv & 1) * 64, g = lid >> 4, r15 = lid & 15;
    #pragma unroll
    for (int nj = 0; nj < 4; ++nj) {
        const int col = n0 + wn + nj * 16 + r15;
        const float bv = bfc[col];
        #pragma unroll
        for (int mi = 0; mi < 4; ++mi)
            #pragma unroll
            for (int j = 0; j < 4; ++j) {
                const int row = m0 + wm + mi * 16 + g * 4 + j;
                out[(size_t)row * 1024 + col] = acc[mi][nj][j] + bv;
            }
    }
}

// ---------------------------------------------------------------------------
// Workspace (64 MiB), round-15 layout:
//   qx4 @0  kx4 @8M  vT @16M  WFt @24M (live: proj..final)
//   Qh @26M  Kh @34M  Vh @42M  WQt @50M  WKt @52M  WVt @54M  CTq @56M
//   After proj: XtQ @26M  XtK @34.03M  CTk @42.05M (over dead Vh/WQt)
//   After conv: ctxb @26M over dead XtQ (attn -> final)
//   ORDER: k_mid (ctrans part) AFTER k_gemm_proj (CTk overlays Vh/WQt).
// ---------------------------------------------------------------------------
extern "C" void kernel_launch(void* const* d_in, const int* in_sizes, int n_in,
                              void* d_out, int out_size, void* d_ws, size_t ws_size,
                              hipStream_t stream)
{
    (void)in_sizes; (void)n_in; (void)out_size; (void)ws_size;
    const float* Q     = (const float*)d_in[0];
    const float* K     = (const float*)d_in[1];
    const float* V     = (const float*)d_in[2];
    // d_in[3] = attn_mask (unused by reference)
    const float* WQ    = (const float*)d_in[4];
    const float* bQ    = (const float*)d_in[5];
    const float* WK    = (const float*)d_in[6];
    const float* bK    = (const float*)d_in[7];
    const float* WV    = (const float*)d_in[8];
    const float* bV    = (const float*)d_in[9];
    const float* Wfc   = (const float*)d_in[10];
    const float* bfc   = (const float*)d_in[11];
    const float* convq = (const float*)d_in[12];
    const float* convk = (const float*)d_in[13];
    const float* w     = (const float*)d_in[14];

    char* ws = (char*)d_ws;
    f16* qx4   = (f16*)(ws + 0);
    f16* kx4   = (f16*)(ws + 8388608);
    f16* vT    = (f16*)(ws + 16777216);
    f16* WFt   = (f16*)(ws + 25165824);
    f16* Qh    = (f16*)(ws + 27262976);
    f16* Kh    = (f16*)(ws + 35651584);
    f16* Vh    = (f16*)(ws + 44040192);
    f16* WQt   = (f16*)(ws + 52428800);
    f16* WKt   = (f16*)(ws + 54525952);
    f16* WVt   = (f16*)(ws + 56623104);
    f16* CTq   = (f16*)(ws + 58720256);
    f16* XtQ   = (f16*)(ws + 27262976);  // over dead Qh (+Kh head)
    f16* XtK   = (f16*)(ws + 35676160);  // over dead Kh (+Vh head)
    f16* CTk   = (f16*)(ws + 44089344);  // over dead Vh (+WQt head) - AFTER proj!
    f16* ctxb  = (f16*)(ws + 27262976);  // over dead XtQ (attn->final)

    dim3 b256(256);

    // 1) merged preproc: cvt Q/K/V + weight transposes
    k_pre<<<16384, b256, 0, stream>>>(Q, K, V, WQ, WK, WV, Wfc,
                                      Qh, Kh, Vh, WQt, WKt, WVt, WFt);
    // 2) projections (64x128 tiles; xw-fast swizzle)
    k_gemm_proj<<<dim3(8, 64, 3), b256, 0, stream>>>(Qh, Kh, Vh, WQt, WKt, WVt,
                                                     bQ, bK, bV, qx4, kx4, vT);
    // 3) merged preproc 2: conv-weight transposes + Xt transpose-pad
    k_mid<<<16640, b256, 0, stream>>>(convq, convk, CTq, CTk,
                                      qx4, kx4, XtQ, XtK);
    // 4) fused conv GEMM + residual (128x128 tiles, z-per-XCD swizzle)
    k_gemm_conv<<<dim3(8, 8, 8), b256, 0, stream>>>(XtQ, XtK, CTq, CTk,
                                                    qx4, kx4, w);
    // 5) flash attention -> ctx (KVBLK=128, 1 barrier/step)
    k_attn<<<dim3(64, 8), b256, 0, stream>>>(qx4, kx4, vT, ctxb);
    // 6) final projection -> f32 output (chunked swizzle)
    k_gemm_final<<<dim3(8, 32), b256, 0, stream>>>(ctxb, WFt, bfc, (float*)d_out);
}